// Round 1
// baseline (342.047 us; speedup 1.0000x reference)
//
#include <hip/hip_runtime.h>
#include <hip/hip_bf16.h>

typedef __attribute__((ext_vector_type(8))) short short8;
typedef __attribute__((ext_vector_type(4))) float floatx4;

#define BATCH 8
#define SEQ 2048
#define DMODEL 768
#define NQKV 2304
#define SCALE 0.03608439182435161f

__device__ __forceinline__ ushort f2bf(float f) {
    union { float f; uint u; } in; in.f = f;
    uint u = in.u;
    return (ushort)((u + 0x7FFFu + ((u >> 16) & 1u)) >> 16);
}
__device__ __forceinline__ float bf2f(ushort h) {
    union { uint u; float f; } o; o.u = ((uint)h) << 16;
    return o.f;
}

// ---------------------------------------------------------------------------
// Kernel 1: qkv = x @ W + b  (fp32 in, bf16 out, scale folded into Q)
// 128x128 tile, BK=32, 256 threads (4 waves, 2x2), mfma 16x16x32 bf16
// ---------------------------------------------------------------------------
__global__ __launch_bounds__(256) void qkv_gemm(
    const float* __restrict__ X,    // [16384][768]
    const float* __restrict__ W,    // [768][2304]
    const float* __restrict__ bias, // [2304]
    ushort* __restrict__ Qs, ushort* __restrict__ Kb, ushort* __restrict__ Vb)
{
    __shared__ ushort As[128][40];   // [m][k], stride 80B (16B multiple)
    __shared__ ushort Bs[128][40];   // [n][k] (transposed W tile)
    const int tid  = threadIdx.x;
    const int m0   = blockIdx.x * 128, n0 = blockIdx.y * 128;
    const int wave = tid >> 6, lane = tid & 63;
    const int wm   = (wave >> 1) * 64, wn = (wave & 1) * 64;
    const int lr   = lane & 15, kg = lane >> 4;
    floatx4 acc[4][4] = {};

    for (int k0 = 0; k0 < DMODEL; k0 += 32) {
        // Stage A: 128 rows x 32 k fp32 -> bf16. 1024 float4 / 256 thr = 4 ea.
        #pragma unroll
        for (int i = 0; i < 4; ++i) {
            int f = tid * 4 + i;                 // 0..1023
            int row = f >> 3, c4 = (f & 7) << 2; // col in elements
            const float4 v = *reinterpret_cast<const float4*>(
                X + (size_t)(m0 + row) * DMODEL + k0 + c4);
            uint2 u;
            u.x = (uint)f2bf(v.x) | ((uint)f2bf(v.y) << 16);
            u.y = (uint)f2bf(v.z) | ((uint)f2bf(v.w) << 16);
            *reinterpret_cast<uint2*>(&As[row][c4]) = u;
        }
        // Stage B: W rows k0..k0+31, cols n0..n0+127, transposed into Bs[n][k]
        {
            int n  = tid & 127;
            int kb = (tid >> 7) << 4;            // 0 or 16
            float tv[16];
            #pragma unroll
            for (int j = 0; j < 16; ++j)
                tv[j] = W[(size_t)(k0 + kb + j) * NQKV + n0 + n];
            uint4 u0, u1;
            u0.x = (uint)f2bf(tv[0])  | ((uint)f2bf(tv[1])  << 16);
            u0.y = (uint)f2bf(tv[2])  | ((uint)f2bf(tv[3])  << 16);
            u0.z = (uint)f2bf(tv[4])  | ((uint)f2bf(tv[5])  << 16);
            u0.w = (uint)f2bf(tv[6])  | ((uint)f2bf(tv[7])  << 16);
            u1.x = (uint)f2bf(tv[8])  | ((uint)f2bf(tv[9])  << 16);
            u1.y = (uint)f2bf(tv[10]) | ((uint)f2bf(tv[11]) << 16);
            u1.z = (uint)f2bf(tv[12]) | ((uint)f2bf(tv[13]) << 16);
            u1.w = (uint)f2bf(tv[14]) | ((uint)f2bf(tv[15]) << 16);
            *reinterpret_cast<uint4*>(&Bs[n][kb])     = u0;
            *reinterpret_cast<uint4*>(&Bs[n][kb + 8]) = u1;
        }
        __syncthreads();
        short8 a[4], b[4];
        #pragma unroll
        for (int i = 0; i < 4; ++i)
            a[i] = *reinterpret_cast<const short8*>(&As[wm + i * 16 + lr][kg * 8]);
        #pragma unroll
        for (int j = 0; j < 4; ++j)
            b[j] = *reinterpret_cast<const short8*>(&Bs[wn + j * 16 + lr][kg * 8]);
        #pragma unroll
        for (int i = 0; i < 4; ++i)
            #pragma unroll
            for (int j = 0; j < 4; ++j)
                acc[i][j] = __builtin_amdgcn_mfma_f32_16x16x32_bf16(a[i], b[j], acc[i][j], 0, 0, 0);
        __syncthreads();
    }

    // Epilogue: D[row][col]: col = lane&15, row = (lane>>4)*4 + r
    #pragma unroll
    for (int i = 0; i < 4; ++i) {
        #pragma unroll
        for (int r = 0; r < 4; ++r) {
            int m = m0 + wm + i * 16 + kg * 4 + r;
            #pragma unroll
            for (int j = 0; j < 4; ++j) {
                int e = n0 + wn + j * 16 + lr;
                float val = acc[i][j][r] + bias[e];
                if (e < DMODEL)
                    Qs[(size_t)m * DMODEL + e] = f2bf(val * SCALE);
                else if (e < 2 * DMODEL)
                    Kb[(size_t)m * DMODEL + (e - DMODEL)] = f2bf(val);
                else
                    Vb[(size_t)m * DMODEL + (e - 2 * DMODEL)] = f2bf(val);
            }
        }
    }
}

// ---------------------------------------------------------------------------
// Kernel 2: S[b] = Qs[b] @ Kb[b]^T   (both [2048][768] bf16, k-contiguous)
// ---------------------------------------------------------------------------
__global__ __launch_bounds__(256) void score_gemm(
    const ushort* __restrict__ Qs, const ushort* __restrict__ Kb,
    ushort* __restrict__ S)
{
    __shared__ ushort As[128][40];
    __shared__ ushort Bs[128][40];
    const int tid  = threadIdx.x;
    const int b    = blockIdx.z;
    const int m0   = blockIdx.x * 128, n0 = blockIdx.y * 128;
    const ushort* Abase = Qs + (size_t)(b * SEQ + m0) * DMODEL;
    const ushort* Bbase = Kb + (size_t)(b * SEQ + n0) * DMODEL;
    ushort* Sb = S + (size_t)b * SEQ * SEQ;
    const int wave = tid >> 6, lane = tid & 63;
    const int wm   = (wave >> 1) * 64, wn = (wave & 1) * 64;
    const int lr   = lane & 15, kg = lane >> 4;
    floatx4 acc[4][4] = {};

    for (int k0 = 0; k0 < DMODEL; k0 += 32) {
        #pragma unroll
        for (int i = 0; i < 2; ++i) {
            int f = tid * 2 + i;                 // 0..511 chunks of 8 bf16
            int row = f >> 2, kc = (f & 3) << 3;
            *reinterpret_cast<uint4*>(&As[row][kc]) =
                *reinterpret_cast<const uint4*>(Abase + (size_t)row * DMODEL + k0 + kc);
            *reinterpret_cast<uint4*>(&Bs[row][kc]) =
                *reinterpret_cast<const uint4*>(Bbase + (size_t)row * DMODEL + k0 + kc);
        }
        __syncthreads();
        short8 a[4], b2[4];
        #pragma unroll
        for (int i = 0; i < 4; ++i)
            a[i] = *reinterpret_cast<const short8*>(&As[wm + i * 16 + lr][kg * 8]);
        #pragma unroll
        for (int j = 0; j < 4; ++j)
            b2[j] = *reinterpret_cast<const short8*>(&Bs[wn + j * 16 + lr][kg * 8]);
        #pragma unroll
        for (int i = 0; i < 4; ++i)
            #pragma unroll
            for (int j = 0; j < 4; ++j)
                acc[i][j] = __builtin_amdgcn_mfma_f32_16x16x32_bf16(a[i], b2[j], acc[i][j], 0, 0, 0);
        __syncthreads();
    }

    #pragma unroll
    for (int i = 0; i < 4; ++i)
        #pragma unroll
        for (int r = 0; r < 4; ++r) {
            int m = m0 + wm + i * 16 + kg * 4 + r;
            #pragma unroll
            for (int j = 0; j < 4; ++j) {
                int n = n0 + wn + j * 16 + lr;
                Sb[(size_t)m * SEQ + n] = f2bf(acc[i][j][r]);
            }
        }
}

// ---------------------------------------------------------------------------
// Kernel 3: row softmax over 2048, in place, bf16. One block per row.
// ---------------------------------------------------------------------------
__global__ __launch_bounds__(256) void softmax_rows(ushort* __restrict__ S) {
    const int row = blockIdx.x;
    ushort* p = S + (size_t)row * SEQ;
    const int tid = threadIdx.x;
    const int wave = tid >> 6, lane = tid & 63;

    short8 v8 = *reinterpret_cast<const short8*>(p + tid * 8);
    float v[8];
    #pragma unroll
    for (int j = 0; j < 8; ++j) v[j] = bf2f((ushort)v8[j]);
    float mx = v[0];
    #pragma unroll
    for (int j = 1; j < 8; ++j) mx = fmaxf(mx, v[j]);
    #pragma unroll
    for (int off = 32; off >= 1; off >>= 1) mx = fmaxf(mx, __shfl_xor(mx, off));
    __shared__ float redm[4], reds[4];
    if (lane == 0) redm[wave] = mx;
    __syncthreads();
    mx = fmaxf(fmaxf(redm[0], redm[1]), fmaxf(redm[2], redm[3]));

    float e[8], s = 0.f;
    #pragma unroll
    for (int j = 0; j < 8; ++j) { e[j] = __expf(v[j] - mx); s += e[j]; }
    #pragma unroll
    for (int off = 32; off >= 1; off >>= 1) s += __shfl_xor(s, off);
    if (lane == 0) reds[wave] = s;
    __syncthreads();
    s = reds[0] + reds[1] + reds[2] + reds[3];
    float inv = 1.f / s;

    short8 o;
    #pragma unroll
    for (int j = 0; j < 8; ++j) o[j] = (short)f2bf(e[j] * inv);
    *reinterpret_cast<short8*>(p + tid * 8) = o;
}

// ---------------------------------------------------------------------------
// Kernel 4: Out[b] = P[b] @ V[b]   (P [2048][2048] bf16, V [2048][768] bf16)
// ---------------------------------------------------------------------------
__global__ __launch_bounds__(256) void pv_gemm(
    const ushort* __restrict__ P, const ushort* __restrict__ Vb,
    float* __restrict__ Out)
{
    __shared__ ushort As[128][40];
    __shared__ ushort Bs[128][40];   // Bs[n][k] (transposed V tile)
    const int tid  = threadIdx.x;
    const int b    = blockIdx.z;
    const int m0   = blockIdx.x * 128, n0 = blockIdx.y * 128;
    const ushort* Abase = P + (size_t)b * SEQ * SEQ + (size_t)m0 * SEQ;
    const ushort* Bbase = Vb + (size_t)b * SEQ * DMODEL;
    const int wave = tid >> 6, lane = tid & 63;
    const int wm   = (wave >> 1) * 64, wn = (wave & 1) * 64;
    const int lr   = lane & 15, kg = lane >> 4;
    floatx4 acc[4][4] = {};

    for (int k0 = 0; k0 < SEQ; k0 += 32) {
        // Stage A (P tile, k-contiguous)
        #pragma unroll
        for (int i = 0; i < 2; ++i) {
            int f = tid * 2 + i;
            int row = f >> 2, kc = (f & 3) << 3;
            *reinterpret_cast<uint4*>(&As[row][kc]) =
                *reinterpret_cast<const uint4*>(Abase + (size_t)row * SEQ + k0 + kc);
        }
        // Stage B (V tile transposed: rows k, cols n -> Bs[n][k])
        {
            int n  = tid & 127;
            int kb = (tid >> 7) << 4;
            ushort tv[16];
            #pragma unroll
            for (int j = 0; j < 16; ++j)
                tv[j] = Bbase[(size_t)(k0 + kb + j) * DMODEL + n0 + n];
            uint4 u0, u1;
            u0.x = (uint)tv[0]  | ((uint)tv[1]  << 16);
            u0.y = (uint)tv[2]  | ((uint)tv[3]  << 16);
            u0.z = (uint)tv[4]  | ((uint)tv[5]  << 16);
            u0.w = (uint)tv[6]  | ((uint)tv[7]  << 16);
            u1.x = (uint)tv[8]  | ((uint)tv[9]  << 16);
            u1.y = (uint)tv[10] | ((uint)tv[11] << 16);
            u1.z = (uint)tv[12] | ((uint)tv[13] << 16);
            u1.w = (uint)tv[14] | ((uint)tv[15] << 16);
            *reinterpret_cast<uint4*>(&Bs[n][kb])     = u0;
            *reinterpret_cast<uint4*>(&Bs[n][kb + 8]) = u1;
        }
        __syncthreads();
        short8 a[4], b2[4];
        #pragma unroll
        for (int i = 0; i < 4; ++i)
            a[i] = *reinterpret_cast<const short8*>(&As[wm + i * 16 + lr][kg * 8]);
        #pragma unroll
        for (int j = 0; j < 4; ++j)
            b2[j] = *reinterpret_cast<const short8*>(&Bs[wn + j * 16 + lr][kg * 8]);
        #pragma unroll
        for (int i = 0; i < 4; ++i)
            #pragma unroll
            for (int j = 0; j < 4; ++j)
                acc[i][j] = __builtin_amdgcn_mfma_f32_16x16x32_bf16(a[i], b2[j], acc[i][j], 0, 0, 0);
        __syncthreads();
    }

    #pragma unroll
    for (int i = 0; i < 4; ++i)
        #pragma unroll
        for (int r = 0; r < 4; ++r) {
            int m = m0 + wm + i * 16 + kg * 4 + r;
            #pragma unroll
            for (int j = 0; j < 4; ++j) {
                int n = n0 + wn + j * 16 + lr;
                Out[((size_t)b * SEQ + m) * DMODEL + n] = acc[i][j][r];
            }
        }
}

// ---------------------------------------------------------------------------
extern "C" void kernel_launch(void* const* d_in, const int* in_sizes, int n_in,
                              void* d_out, int out_size, void* d_ws, size_t ws_size,
                              hipStream_t stream) {
    const float* X    = (const float*)d_in[0];
    const float* W    = (const float*)d_in[1];
    const float* bias = (const float*)d_in[2];
    float* Out = (float*)d_out;

    // Workspace layout (bytes): Q 25.2M | K 25.2M | V 25.2M | S 67.1M = 142.6MB
    ushort* Qs = (ushort*)d_ws;
    ushort* Kb = Qs + (size_t)BATCH * SEQ * DMODEL;
    ushort* Vb = Kb + (size_t)BATCH * SEQ * DMODEL;
    ushort* S  = Vb + (size_t)BATCH * SEQ * DMODEL;

    qkv_gemm<<<dim3(128, 18), 256, 0, stream>>>(X, W, bias, Qs, Kb, Vb);
    score_gemm<<<dim3(16, 16, 8), 256, 0, stream>>>(Qs, Kb, S);
    softmax_rows<<<BATCH * SEQ, 256, 0, stream>>>(S);
    pv_gemm<<<dim3(16, 6, 8), 256, 0, stream>>>(S, Vb, Out);
}

// Round 2
// 298.138 us; speedup vs baseline: 1.1473x; 1.1473x over previous
//
#include <hip/hip_runtime.h>
#include <hip/hip_bf16.h>

typedef __attribute__((ext_vector_type(8))) short short8;
typedef __attribute__((ext_vector_type(4))) float floatx4;

#define BATCH 8
#define SEQ 2048
#define DMODEL 768
#define NQKV 2304
#define SCALE 0.03608439182435161f

__device__ __forceinline__ ushort f2bf(float f) {
    union { float f; uint u; } in; in.f = f;
    uint u = in.u;
    return (ushort)((u + 0x7FFFu + ((u >> 16) & 1u)) >> 16);
}
__device__ __forceinline__ float bf2f(ushort h) {
    union { uint u; float f; } o; o.u = ((uint)h) << 16;
    return o.f;
}

// async global->LDS, 16B per lane. lds ptr must be wave-uniform; HW scatters
// to lds + lane*16. Global address is per-lane.
__device__ __forceinline__ void async_copy16(void* lds_uniform, const void* gaddr) {
    __builtin_amdgcn_global_load_lds(
        (const __attribute__((address_space(1))) void*)gaddr,
        (__attribute__((address_space(3))) void*)lds_uniform,
        16, 0, 0);
}

// Stage a [128][32] bf16 tile (8192B) from row-major global (ld elements)
// into linear LDS. 4 waves x 2 instrs; chunk c covers rows c*16..c*16+15.
__device__ __forceinline__ void stage128x32(ushort* lds, const ushort* gbase,
                                            size_t ld, int k0, int wave, int lane) {
    #pragma unroll
    for (int t = 0; t < 2; ++t) {
        const int chunk = wave * 2 + t;
        const int row = chunk * 16 + (lane >> 2);
        const ushort* g = gbase + (size_t)row * ld + k0 + (lane & 3) * 8;
        async_copy16(lds + chunk * 512, g);
    }
}

// ---------------------------------------------------------------------------
// Kernel 0a: X fp32 -> bf16
// ---------------------------------------------------------------------------
__global__ __launch_bounds__(256) void convert_x(const float* __restrict__ X,
                                                 ushort* __restrict__ Xb) {
    const int total = (BATCH * SEQ * DMODEL) / 8;
    for (int i = blockIdx.x * 256 + threadIdx.x; i < total; i += gridDim.x * 256) {
        const float4 v0 = reinterpret_cast<const float4*>(X)[(size_t)i * 2];
        const float4 v1 = reinterpret_cast<const float4*>(X)[(size_t)i * 2 + 1];
        uint4 u;
        u.x = (uint)f2bf(v0.x) | ((uint)f2bf(v0.y) << 16);
        u.y = (uint)f2bf(v0.z) | ((uint)f2bf(v0.w) << 16);
        u.z = (uint)f2bf(v1.x) | ((uint)f2bf(v1.y) << 16);
        u.w = (uint)f2bf(v1.z) | ((uint)f2bf(v1.w) << 16);
        reinterpret_cast<uint4*>(Xb)[i] = u;
    }
}

// ---------------------------------------------------------------------------
// Kernel 0b: W [768][2304] fp32 -> Wt [2304][768] bf16 (transpose)
// ---------------------------------------------------------------------------
__global__ __launch_bounds__(256) void convert_wt(const float* __restrict__ W,
                                                  ushort* __restrict__ Wt) {
    __shared__ float tile[32][33];
    const int n0 = blockIdx.x * 32, k0 = blockIdx.y * 32;
    const int tx = threadIdx.x & 31, ty = threadIdx.x >> 5;
    #pragma unroll
    for (int i = 0; i < 32; i += 8)
        tile[ty + i][tx] = W[(size_t)(k0 + ty + i) * NQKV + n0 + tx];
    __syncthreads();
    #pragma unroll
    for (int i = 0; i < 32; i += 8)
        Wt[(size_t)(n0 + ty + i) * DMODEL + k0 + tx] = f2bf(tile[tx][ty + i]);
}

// ---------------------------------------------------------------------------
// Kernel 0c: V [b][n][d] bf16 -> Vt [b][d][n] bf16 (transpose)
// ---------------------------------------------------------------------------
__global__ __launch_bounds__(256) void transpose_v(const ushort* __restrict__ Vb,
                                                   ushort* __restrict__ Vt) {
    __shared__ ushort tile[32][33];
    const int b = blockIdx.z;
    const int n0 = blockIdx.x * 32, d0 = blockIdx.y * 32;
    const ushort* src = Vb + (size_t)b * SEQ * DMODEL;
    ushort* dst = Vt + (size_t)b * DMODEL * SEQ;
    const int tx = threadIdx.x & 31, ty = threadIdx.x >> 5;
    #pragma unroll
    for (int i = 0; i < 32; i += 8)
        tile[ty + i][tx] = src[(size_t)(n0 + ty + i) * DMODEL + d0 + tx];
    __syncthreads();
    #pragma unroll
    for (int i = 0; i < 32; i += 8)
        dst[(size_t)(d0 + ty + i) * SEQ + n0 + tx] = tile[tx][ty + i];
}

// ---------------------------------------------------------------------------
// Kernel 1: qkv = Xb @ Wt^T + b  (bf16 in, bf16 out, scale folded into Q)
// m97 structure: 128x128 tile, BK=32, global_load_lds staging, linear LDS.
// ---------------------------------------------------------------------------
__global__ __launch_bounds__(256) void qkv_gemm(
    const ushort* __restrict__ Xb,   // [16384][768]
    const ushort* __restrict__ Wt,   // [2304][768]
    const float* __restrict__ bias,  // [2304]
    ushort* __restrict__ Qs, ushort* __restrict__ Kb, ushort* __restrict__ Vb)
{
    __shared__ ushort As[128 * 32];
    __shared__ ushort Bs[128 * 32];
    const int tid  = threadIdx.x;
    const int m0   = blockIdx.x * 128, n0 = blockIdx.y * 128;
    const int wave = tid >> 6, lane = tid & 63;
    const int wm   = (wave >> 1) * 64, wn = (wave & 1) * 64;
    const int lr   = lane & 15, kg = lane >> 4;
    const ushort* Abase = Xb + (size_t)m0 * DMODEL;
    const ushort* Bbase = Wt + (size_t)n0 * DMODEL;
    floatx4 acc[4][4] = {};

    for (int k0 = 0; k0 < DMODEL; k0 += 32) {
        stage128x32(As, Abase, DMODEL, k0, wave, lane);
        stage128x32(Bs, Bbase, DMODEL, k0, wave, lane);
        __syncthreads();
        short8 a[4], b[4];
        #pragma unroll
        for (int i = 0; i < 4; ++i)
            a[i] = *reinterpret_cast<const short8*>(&As[(wm + i * 16 + lr) * 32 + kg * 8]);
        #pragma unroll
        for (int j = 0; j < 4; ++j)
            b[j] = *reinterpret_cast<const short8*>(&Bs[(wn + j * 16 + lr) * 32 + kg * 8]);
        #pragma unroll
        for (int i = 0; i < 4; ++i)
            #pragma unroll
            for (int j = 0; j < 4; ++j)
                acc[i][j] = __builtin_amdgcn_mfma_f32_16x16x32_bf16(a[i], b[j], acc[i][j], 0, 0, 0);
        __syncthreads();
    }

    #pragma unroll
    for (int i = 0; i < 4; ++i) {
        #pragma unroll
        for (int r = 0; r < 4; ++r) {
            int m = m0 + wm + i * 16 + kg * 4 + r;
            #pragma unroll
            for (int j = 0; j < 4; ++j) {
                int e = n0 + wn + j * 16 + lr;
                float val = acc[i][j][r] + bias[e];
                if (e < DMODEL)
                    Qs[(size_t)m * DMODEL + e] = f2bf(val * SCALE);
                else if (e < 2 * DMODEL)
                    Kb[(size_t)m * DMODEL + (e - DMODEL)] = f2bf(val);
                else
                    Vb[(size_t)m * DMODEL + (e - 2 * DMODEL)] = f2bf(val);
            }
        }
    }
}

// ---------------------------------------------------------------------------
// Kernel 2: S[b] = Qs[b] @ Kb[b]^T
// ---------------------------------------------------------------------------
__global__ __launch_bounds__(256) void score_gemm(
    const ushort* __restrict__ Qs, const ushort* __restrict__ Kb,
    ushort* __restrict__ S)
{
    __shared__ ushort As[128 * 32];
    __shared__ ushort Bs[128 * 32];
    const int tid  = threadIdx.x;
    const int b    = blockIdx.z;
    const int m0   = blockIdx.x * 128, n0 = blockIdx.y * 128;
    const ushort* Abase = Qs + (size_t)(b * SEQ + m0) * DMODEL;
    const ushort* Bbase = Kb + (size_t)(b * SEQ + n0) * DMODEL;
    ushort* Sb = S + (size_t)b * SEQ * SEQ;
    const int wave = tid >> 6, lane = tid & 63;
    const int wm   = (wave >> 1) * 64, wn = (wave & 1) * 64;
    const int lr   = lane & 15, kg = lane >> 4;
    floatx4 acc[4][4] = {};

    for (int k0 = 0; k0 < DMODEL; k0 += 32) {
        stage128x32(As, Abase, DMODEL, k0, wave, lane);
        stage128x32(Bs, Bbase, DMODEL, k0, wave, lane);
        __syncthreads();
        short8 a[4], b2[4];
        #pragma unroll
        for (int i = 0; i < 4; ++i)
            a[i] = *reinterpret_cast<const short8*>(&As[(wm + i * 16 + lr) * 32 + kg * 8]);
        #pragma unroll
        for (int j = 0; j < 4; ++j)
            b2[j] = *reinterpret_cast<const short8*>(&Bs[(wn + j * 16 + lr) * 32 + kg * 8]);
        #pragma unroll
        for (int i = 0; i < 4; ++i)
            #pragma unroll
            for (int j = 0; j < 4; ++j)
                acc[i][j] = __builtin_amdgcn_mfma_f32_16x16x32_bf16(a[i], b2[j], acc[i][j], 0, 0, 0);
        __syncthreads();
    }

    #pragma unroll
    for (int i = 0; i < 4; ++i)
        #pragma unroll
        for (int r = 0; r < 4; ++r) {
            int m = m0 + wm + i * 16 + kg * 4 + r;
            #pragma unroll
            for (int j = 0; j < 4; ++j) {
                int n = n0 + wn + j * 16 + lr;
                Sb[(size_t)m * SEQ + n] = f2bf(acc[i][j][r]);
            }
        }
}

// ---------------------------------------------------------------------------
// Kernel 3: row softmax over 2048, in place, bf16. One block per row.
// ---------------------------------------------------------------------------
__global__ __launch_bounds__(256) void softmax_rows(ushort* __restrict__ S) {
    const int row = blockIdx.x;
    ushort* p = S + (size_t)row * SEQ;
    const int tid = threadIdx.x;
    const int wave = tid >> 6, lane = tid & 63;

    short8 v8 = *reinterpret_cast<const short8*>(p + tid * 8);
    float v[8];
    #pragma unroll
    for (int j = 0; j < 8; ++j) v[j] = bf2f((ushort)v8[j]);
    float mx = v[0];
    #pragma unroll
    for (int j = 1; j < 8; ++j) mx = fmaxf(mx, v[j]);
    #pragma unroll
    for (int off = 32; off >= 1; off >>= 1) mx = fmaxf(mx, __shfl_xor(mx, off));
    __shared__ float redm[4], reds[4];
    if (lane == 0) redm[wave] = mx;
    __syncthreads();
    mx = fmaxf(fmaxf(redm[0], redm[1]), fmaxf(redm[2], redm[3]));

    float e[8], s = 0.f;
    #pragma unroll
    for (int j = 0; j < 8; ++j) { e[j] = __expf(v[j] - mx); s += e[j]; }
    #pragma unroll
    for (int off = 32; off >= 1; off >>= 1) s += __shfl_xor(s, off);
    if (lane == 0) reds[wave] = s;
    __syncthreads();
    s = reds[0] + reds[1] + reds[2] + reds[3];
    float inv = 1.f / s;

    short8 o;
    #pragma unroll
    for (int j = 0; j < 8; ++j) o[j] = (short)f2bf(e[j] * inv);
    *reinterpret_cast<short8*>(p + tid * 8) = o;
}

// ---------------------------------------------------------------------------
// Kernel 4: Out[b] = P[b] @ Vt[b]^T  (P [2048][2048], Vt [768][2048], both bf16)
// ---------------------------------------------------------------------------
__global__ __launch_bounds__(256) void pv_gemm(
    const ushort* __restrict__ P, const ushort* __restrict__ Vt,
    float* __restrict__ Out)
{
    __shared__ ushort As[128 * 32];
    __shared__ ushort Bs[128 * 32];
    const int tid  = threadIdx.x;
    const int b    = blockIdx.z;
    const int m0   = blockIdx.x * 128, n0 = blockIdx.y * 128;
    const ushort* Abase = P + (size_t)b * SEQ * SEQ + (size_t)m0 * SEQ;
    const ushort* Bbase = Vt + (size_t)b * DMODEL * SEQ + (size_t)n0 * SEQ;
    const int wave = tid >> 6, lane = tid & 63;
    const int wm   = (wave >> 1) * 64, wn = (wave & 1) * 64;
    const int lr   = lane & 15, kg = lane >> 4;
    floatx4 acc[4][4] = {};

    for (int k0 = 0; k0 < SEQ; k0 += 32) {
        stage128x32(As, Abase, SEQ, k0, wave, lane);
        stage128x32(Bs, Bbase, SEQ, k0, wave, lane);
        __syncthreads();
        short8 a[4], b2[4];
        #pragma unroll
        for (int i = 0; i < 4; ++i)
            a[i] = *reinterpret_cast<const short8*>(&As[(wm + i * 16 + lr) * 32 + kg * 8]);
        #pragma unroll
        for (int j = 0; j < 4; ++j)
            b2[j] = *reinterpret_cast<const short8*>(&Bs[(wn + j * 16 + lr) * 32 + kg * 8]);
        #pragma unroll
        for (int i = 0; i < 4; ++i)
            #pragma unroll
            for (int j = 0; j < 4; ++j)
                acc[i][j] = __builtin_amdgcn_mfma_f32_16x16x32_bf16(a[i], b2[j], acc[i][j], 0, 0, 0);
        __syncthreads();
    }

    #pragma unroll
    for (int i = 0; i < 4; ++i)
        #pragma unroll
        for (int r = 0; r < 4; ++r) {
            int m = m0 + wm + i * 16 + kg * 4 + r;
            #pragma unroll
            for (int j = 0; j < 4; ++j) {
                int n = n0 + wn + j * 16 + lr;
                Out[((size_t)b * SEQ + m) * DMODEL + n] = acc[i][j][r];
            }
        }
}

// ---------------------------------------------------------------------------
extern "C" void kernel_launch(void* const* d_in, const int* in_sizes, int n_in,
                              void* d_out, int out_size, void* d_ws, size_t ws_size,
                              hipStream_t stream) {
    const float* X    = (const float*)d_in[0];
    const float* W    = (const float*)d_in[1];
    const float* bias = (const float*)d_in[2];
    float* Out = (float*)d_out;

    // Workspace layout (bytes), total 160 MiB:
    //   [0, 67.1M):  S  (scores)  -- aliases Xb [0,25.2M) + Wt [25.2M,28.7M),
    //                                which are dead before score_gemm runs.
    //   [67.1M ...): Q | K | V | Vt   (25.2M each)
    char* ws = (char*)d_ws;
    ushort* S  = (ushort*)ws;
    ushort* Xb = (ushort*)ws;
    ushort* Wt = (ushort*)(ws + (size_t)BATCH * SEQ * DMODEL * 2);
    ushort* Qs = (ushort*)(ws + (size_t)BATCH * SEQ * SEQ * 2);
    ushort* Kb = Qs + (size_t)BATCH * SEQ * DMODEL;
    ushort* Vb = Kb + (size_t)BATCH * SEQ * DMODEL;
    ushort* Vt = Vb + (size_t)BATCH * SEQ * DMODEL;

    convert_x<<<2048, 256, 0, stream>>>(X, Xb);
    convert_wt<<<dim3(NQKV / 32, DMODEL / 32), 256, 0, stream>>>(W, Wt);
    qkv_gemm<<<dim3(128, 18), 256, 0, stream>>>(Xb, Wt, bias, Qs, Kb, Vb);
    transpose_v<<<dim3(SEQ / 32, DMODEL / 32, BATCH), 256, 0, stream>>>(Vb, Vt);
    score_gemm<<<dim3(16, 16, 8), 256, 0, stream>>>(Qs, Kb, S);
    softmax_rows<<<BATCH * SEQ, 256, 0, stream>>>(S);
    pv_gemm<<<dim3(16, 6, 8), 256, 0, stream>>>(S, Vt, Out);
}

// Round 3
// 282.440 us; speedup vs baseline: 1.2110x; 1.0556x over previous
//
#include <hip/hip_runtime.h>
#include <hip/hip_bf16.h>

typedef __attribute__((ext_vector_type(8))) short short8;
typedef __attribute__((ext_vector_type(4))) float floatx4;

#define BATCH 8
#define SEQ 2048
#define DMODEL 768
#define NQKV 2304
#define SCALE 0.03608439182435161f

__device__ __forceinline__ ushort f2bf(float f) {
    union { float f; uint u; } in; in.f = f;
    uint u = in.u;
    return (ushort)((u + 0x7FFFu + ((u >> 16) & 1u)) >> 16);
}
__device__ __forceinline__ float bf2f(ushort h) {
    union { uint u; float f; } o; o.u = ((uint)h) << 16;
    return o.f;
}

// async global->LDS, 16B per lane. lds ptr must be wave-uniform; HW scatters
// to lds + lane*16. Global address is per-lane.
__device__ __forceinline__ void async_copy16(void* lds_uniform, const void* gaddr) {
    __builtin_amdgcn_global_load_lds(
        (const __attribute__((address_space(1))) void*)gaddr,
        (__attribute__((address_space(3))) void*)lds_uniform,
        16, 0, 0);
}

// Stage a [128][64] bf16 tile (16 KB) from row-major global (ld elements) into
// LINEAR LDS, with the column-chunk XOR-swizzle applied on the GLOBAL source
// address (rule #21: linear dest + inverse-swz source; reader applies same XOR).
// Physical 16B-slot p of row r holds global chunk (p ^ (r&7)).
// 4 waves x 4 instrs; chunk t covers 8 rows (8 rows x 128B = 1024B = wave-width).
__device__ __forceinline__ void stage128x64(ushort* lds, const ushort* gbase,
                                            size_t ld, int k0, int wave, int lane) {
    const int sub = lane >> 3;          // row within 8-row chunk (== r&7)
    const int cc  = (lane & 7) ^ sub;   // swizzled source column chunk
    #pragma unroll
    for (int t = 0; t < 4; ++t) {
        const int chunk = wave * 4 + t;     // 0..15
        const int row   = chunk * 8 + sub;
        const ushort* g = gbase + (size_t)row * ld + k0 + cc * 8;
        async_copy16(lds + chunk * 512, g);
    }
}

// ---------------------------------------------------------------------------
// Kernel 0a: X fp32 -> bf16
// ---------------------------------------------------------------------------
__global__ __launch_bounds__(256) void convert_x(const float* __restrict__ X,
                                                 ushort* __restrict__ Xb) {
    const int total = (BATCH * SEQ * DMODEL) / 8;
    for (int i = blockIdx.x * 256 + threadIdx.x; i < total; i += gridDim.x * 256) {
        const float4 v0 = reinterpret_cast<const float4*>(X)[(size_t)i * 2];
        const float4 v1 = reinterpret_cast<const float4*>(X)[(size_t)i * 2 + 1];
        uint4 u;
        u.x = (uint)f2bf(v0.x) | ((uint)f2bf(v0.y) << 16);
        u.y = (uint)f2bf(v0.z) | ((uint)f2bf(v0.w) << 16);
        u.z = (uint)f2bf(v1.x) | ((uint)f2bf(v1.y) << 16);
        u.w = (uint)f2bf(v1.z) | ((uint)f2bf(v1.w) << 16);
        reinterpret_cast<uint4*>(Xb)[i] = u;
    }
}

// ---------------------------------------------------------------------------
// Kernel 0b: W [768][2304] fp32 -> Wt [2304][768] bf16 (transpose)
// ---------------------------------------------------------------------------
__global__ __launch_bounds__(256) void convert_wt(const float* __restrict__ W,
                                                  ushort* __restrict__ Wt) {
    __shared__ float tile[32][33];
    const int n0 = blockIdx.x * 32, k0 = blockIdx.y * 32;
    const int tx = threadIdx.x & 31, ty = threadIdx.x >> 5;
    #pragma unroll
    for (int i = 0; i < 32; i += 8)
        tile[ty + i][tx] = W[(size_t)(k0 + ty + i) * NQKV + n0 + tx];
    __syncthreads();
    #pragma unroll
    for (int i = 0; i < 32; i += 8)
        Wt[(size_t)(n0 + ty + i) * DMODEL + k0 + tx] = f2bf(tile[tx][ty + i]);
}

// ---------------------------------------------------------------------------
// Kernel 0c: V [b][n][d] bf16 -> Vt [b][d][n] bf16 (transpose)
// ---------------------------------------------------------------------------
__global__ __launch_bounds__(256) void transpose_v(const ushort* __restrict__ Vb,
                                                   ushort* __restrict__ Vt) {
    __shared__ ushort tile[32][33];
    const int b = blockIdx.z;
    const int n0 = blockIdx.x * 32, d0 = blockIdx.y * 32;
    const ushort* src = Vb + (size_t)b * SEQ * DMODEL;
    ushort* dst = Vt + (size_t)b * DMODEL * SEQ;
    const int tx = threadIdx.x & 31, ty = threadIdx.x >> 5;
    #pragma unroll
    for (int i = 0; i < 32; i += 8)
        tile[ty + i][tx] = src[(size_t)(n0 + ty + i) * DMODEL + d0 + tx];
    __syncthreads();
    #pragma unroll
    for (int i = 0; i < 32; i += 8)
        dst[(size_t)(d0 + ty + i) * SEQ + n0 + tx] = tile[tx][ty + i];
}

// ---------------------------------------------------------------------------
// Shared GEMM body macro pieces: 128x128 tile, BK=64, 4 waves (2x2),
// global_load_lds staging with source-side swizzle, 32 MFMA / K-step.
// Frag read: logical chunk c = ks*4+kg -> physical slot c ^ (row&7).
// ---------------------------------------------------------------------------

// ---------------------------------------------------------------------------
// Kernel 1: qkv = Xb @ Wt^T + b  (bf16 in, bf16 out, scale folded into Q)
// ---------------------------------------------------------------------------
__global__ __launch_bounds__(256) void qkv_gemm(
    const ushort* __restrict__ Xb,   // [16384][768]
    const ushort* __restrict__ Wt,   // [2304][768]
    const float* __restrict__ bias,  // [2304]
    ushort* __restrict__ Qs, ushort* __restrict__ Kb, ushort* __restrict__ Vb)
{
    __shared__ ushort As[128 * 64];
    __shared__ ushort Bs[128 * 64];
    const int tid  = threadIdx.x;
    const int m0   = blockIdx.x * 128, n0 = blockIdx.y * 128;
    const int wave = tid >> 6, lane = tid & 63;
    const int wm   = (wave >> 1) * 64, wn = (wave & 1) * 64;
    const int lr   = lane & 15, kg = lane >> 4;
    const int xr   = lr & 7;
    const ushort* Abase = Xb + (size_t)m0 * DMODEL;
    const ushort* Bbase = Wt + (size_t)n0 * DMODEL;
    floatx4 acc[4][4] = {};

    for (int k0 = 0; k0 < DMODEL; k0 += 64) {
        stage128x64(As, Abase, DMODEL, k0, wave, lane);
        stage128x64(Bs, Bbase, DMODEL, k0, wave, lane);
        __syncthreads();
        #pragma unroll
        for (int ks = 0; ks < 2; ++ks) {
            const int slot = ((ks * 4 + kg) ^ xr) * 8;
            short8 a[4], b[4];
            #pragma unroll
            for (int i = 0; i < 4; ++i)
                a[i] = *reinterpret_cast<const short8*>(&As[(wm + i * 16 + lr) * 64 + slot]);
            #pragma unroll
            for (int j = 0; j < 4; ++j)
                b[j] = *reinterpret_cast<const short8*>(&Bs[(wn + j * 16 + lr) * 64 + slot]);
            #pragma unroll
            for (int i = 0; i < 4; ++i)
                #pragma unroll
                for (int j = 0; j < 4; ++j)
                    acc[i][j] = __builtin_amdgcn_mfma_f32_16x16x32_bf16(a[i], b[j], acc[i][j], 0, 0, 0);
        }
        __syncthreads();
    }

    #pragma unroll
    for (int i = 0; i < 4; ++i) {
        #pragma unroll
        for (int r = 0; r < 4; ++r) {
            int m = m0 + wm + i * 16 + kg * 4 + r;
            #pragma unroll
            for (int j = 0; j < 4; ++j) {
                int e = n0 + wn + j * 16 + lr;
                float val = acc[i][j][r] + bias[e];
                if (e < DMODEL)
                    Qs[(size_t)m * DMODEL + e] = f2bf(val * SCALE);
                else if (e < 2 * DMODEL)
                    Kb[(size_t)m * DMODEL + (e - DMODEL)] = f2bf(val);
                else
                    Vb[(size_t)m * DMODEL + (e - 2 * DMODEL)] = f2bf(val);
            }
        }
    }
}

// ---------------------------------------------------------------------------
// Kernel 2: S[b] = Qs[b] @ Kb[b]^T
// ---------------------------------------------------------------------------
__global__ __launch_bounds__(256) void score_gemm(
    const ushort* __restrict__ Qs, const ushort* __restrict__ Kb,
    ushort* __restrict__ S)
{
    __shared__ ushort As[128 * 64];
    __shared__ ushort Bs[128 * 64];
    const int tid  = threadIdx.x;
    const int b    = blockIdx.z;
    const int m0   = blockIdx.x * 128, n0 = blockIdx.y * 128;
    const ushort* Abase = Qs + (size_t)(b * SEQ + m0) * DMODEL;
    const ushort* Bbase = Kb + (size_t)(b * SEQ + n0) * DMODEL;
    ushort* Sb = S + (size_t)b * SEQ * SEQ;
    const int wave = tid >> 6, lane = tid & 63;
    const int wm   = (wave >> 1) * 64, wn = (wave & 1) * 64;
    const int lr   = lane & 15, kg = lane >> 4;
    const int xr   = lr & 7;
    floatx4 acc[4][4] = {};

    for (int k0 = 0; k0 < DMODEL; k0 += 64) {
        stage128x64(As, Abase, DMODEL, k0, wave, lane);
        stage128x64(Bs, Bbase, DMODEL, k0, wave, lane);
        __syncthreads();
        #pragma unroll
        for (int ks = 0; ks < 2; ++ks) {
            const int slot = ((ks * 4 + kg) ^ xr) * 8;
            short8 a[4], b2[4];
            #pragma unroll
            for (int i = 0; i < 4; ++i)
                a[i] = *reinterpret_cast<const short8*>(&As[(wm + i * 16 + lr) * 64 + slot]);
            #pragma unroll
            for (int j = 0; j < 4; ++j)
                b2[j] = *reinterpret_cast<const short8*>(&Bs[(wn + j * 16 + lr) * 64 + slot]);
            #pragma unroll
            for (int i = 0; i < 4; ++i)
                #pragma unroll
                for (int j = 0; j < 4; ++j)
                    acc[i][j] = __builtin_amdgcn_mfma_f32_16x16x32_bf16(a[i], b2[j], acc[i][j], 0, 0, 0);
        }
        __syncthreads();
    }

    #pragma unroll
    for (int i = 0; i < 4; ++i)
        #pragma unroll
        for (int r = 0; r < 4; ++r) {
            int m = m0 + wm + i * 16 + kg * 4 + r;
            #pragma unroll
            for (int j = 0; j < 4; ++j) {
                int n = n0 + wn + j * 16 + lr;
                Sb[(size_t)m * SEQ + n] = f2bf(acc[i][j][r]);
            }
        }
}

// ---------------------------------------------------------------------------
// Kernel 3: row softmax over 2048, in place, bf16. One block per row.
// ---------------------------------------------------------------------------
__global__ __launch_bounds__(256) void softmax_rows(ushort* __restrict__ S) {
    const int row = blockIdx.x;
    ushort* p = S + (size_t)row * SEQ;
    const int tid = threadIdx.x;
    const int wave = tid >> 6, lane = tid & 63;

    short8 v8 = *reinterpret_cast<const short8*>(p + tid * 8);
    float v[8];
    #pragma unroll
    for (int j = 0; j < 8; ++j) v[j] = bf2f((ushort)v8[j]);
    float mx = v[0];
    #pragma unroll
    for (int j = 1; j < 8; ++j) mx = fmaxf(mx, v[j]);
    #pragma unroll
    for (int off = 32; off >= 1; off >>= 1) mx = fmaxf(mx, __shfl_xor(mx, off));
    __shared__ float redm[4], reds[4];
    if (lane == 0) redm[wave] = mx;
    __syncthreads();
    mx = fmaxf(fmaxf(redm[0], redm[1]), fmaxf(redm[2], redm[3]));

    float e[8], s = 0.f;
    #pragma unroll
    for (int j = 0; j < 8; ++j) { e[j] = __expf(v[j] - mx); s += e[j]; }
    #pragma unroll
    for (int off = 32; off >= 1; off >>= 1) s += __shfl_xor(s, off);
    if (lane == 0) reds[wave] = s;
    __syncthreads();
    s = reds[0] + reds[1] + reds[2] + reds[3];
    float inv = 1.f / s;

    short8 o;
    #pragma unroll
    for (int j = 0; j < 8; ++j) o[j] = (short)f2bf(e[j] * inv);
    *reinterpret_cast<short8*>(p + tid * 8) = o;
}

// ---------------------------------------------------------------------------
// Kernel 4: Out[b] = P[b] @ Vt[b]^T  (P [2048][2048], Vt [768][2048], both bf16)
// ---------------------------------------------------------------------------
__global__ __launch_bounds__(256) void pv_gemm(
    const ushort* __restrict__ P, const ushort* __restrict__ Vt,
    float* __restrict__ Out)
{
    __shared__ ushort As[128 * 64];
    __shared__ ushort Bs[128 * 64];
    const int tid  = threadIdx.x;
    const int b    = blockIdx.z;
    const int m0   = blockIdx.x * 128, n0 = blockIdx.y * 128;
    const ushort* Abase = P + (size_t)b * SEQ * SEQ + (size_t)m0 * SEQ;
    const ushort* Bbase = Vt + (size_t)b * DMODEL * SEQ + (size_t)n0 * SEQ;
    const int wave = tid >> 6, lane = tid & 63;
    const int wm   = (wave >> 1) * 64, wn = (wave & 1) * 64;
    const int lr   = lane & 15, kg = lane >> 4;
    const int xr   = lr & 7;
    floatx4 acc[4][4] = {};

    for (int k0 = 0; k0 < SEQ; k0 += 64) {
        stage128x64(As, Abase, SEQ, k0, wave, lane);
        stage128x64(Bs, Bbase, SEQ, k0, wave, lane);
        __syncthreads();
        #pragma unroll
        for (int ks = 0; ks < 2; ++ks) {
            const int slot = ((ks * 4 + kg) ^ xr) * 8;
            short8 a[4], b2[4];
            #pragma unroll
            for (int i = 0; i < 4; ++i)
                a[i] = *reinterpret_cast<const short8*>(&As[(wm + i * 16 + lr) * 64 + slot]);
            #pragma unroll
            for (int j = 0; j < 4; ++j)
                b2[j] = *reinterpret_cast<const short8*>(&Bs[(wn + j * 16 + lr) * 64 + slot]);
            #pragma unroll
            for (int i = 0; i < 4; ++i)
                #pragma unroll
                for (int j = 0; j < 4; ++j)
                    acc[i][j] = __builtin_amdgcn_mfma_f32_16x16x32_bf16(a[i], b2[j], acc[i][j], 0, 0, 0);
        }
        __syncthreads();
    }

    #pragma unroll
    for (int i = 0; i < 4; ++i)
        #pragma unroll
        for (int r = 0; r < 4; ++r) {
            int m = m0 + wm + i * 16 + kg * 4 + r;
            #pragma unroll
            for (int j = 0; j < 4; ++j) {
                int n = n0 + wn + j * 16 + lr;
                Out[((size_t)b * SEQ + m) * DMODEL + n] = acc[i][j][r];
            }
        }
}

// ---------------------------------------------------------------------------
extern "C" void kernel_launch(void* const* d_in, const int* in_sizes, int n_in,
                              void* d_out, int out_size, void* d_ws, size_t ws_size,
                              hipStream_t stream) {
    const float* X    = (const float*)d_in[0];
    const float* W    = (const float*)d_in[1];
    const float* bias = (const float*)d_in[2];
    float* Out = (float*)d_out;

    // Workspace layout (bytes), total 160 MiB:
    //   [0, 67.1M):  S  (scores)  -- aliases Xb [0,25.2M) + Wt [25.2M,28.7M),
    //                                which are dead before score_gemm runs.
    //   [67.1M ...): Q | K | V | Vt   (25.2M each)
    char* ws = (char*)d_ws;
    ushort* S  = (ushort*)ws;
    ushort* Xb = (ushort*)ws;
    ushort* Wt = (ushort*)(ws + (size_t)BATCH * SEQ * DMODEL * 2);
    ushort* Qs = (ushort*)(ws + (size_t)BATCH * SEQ * SEQ * 2);
    ushort* Kb = Qs + (size_t)BATCH * SEQ * DMODEL;
    ushort* Vb = Kb + (size_t)BATCH * SEQ * DMODEL;
    ushort* Vt = Vb + (size_t)BATCH * SEQ * DMODEL;

    convert_x<<<2048, 256, 0, stream>>>(X, Xb);
    convert_wt<<<dim3(NQKV / 32, DMODEL / 32), 256, 0, stream>>>(W, Wt);
    qkv_gemm<<<dim3(128, 18), 256, 0, stream>>>(Xb, Wt, bias, Qs, Kb, Vb);
    transpose_v<<<dim3(SEQ / 32, DMODEL / 32, BATCH), 256, 0, stream>>>(Vb, Vt);
    score_gemm<<<dim3(16, 16, 8), 256, 0, stream>>>(Qs, Kb, S);
    softmax_rows<<<BATCH * SEQ, 256, 0, stream>>>(S);
    pv_gemm<<<dim3(16, 6, 8), 256, 0, stream>>>(S, Vt, Out);
}

// Round 4
// 267.414 us; speedup vs baseline: 1.2791x; 1.0562x over previous
//
#include <hip/hip_runtime.h>
#include <hip/hip_bf16.h>

typedef __attribute__((ext_vector_type(8))) short short8;
typedef __attribute__((ext_vector_type(4))) float floatx4;

#define BATCH 8
#define SEQ 2048
#define DMODEL 768
#define NQKV 2304
#define SCALE 0.03608439182435161f

__device__ __forceinline__ ushort f2bf(float f) {
    union { float f; uint u; } in; in.f = f;
    uint u = in.u;
    return (ushort)((u + 0x7FFFu + ((u >> 16) & 1u)) >> 16);
}
__device__ __forceinline__ float bf2f(ushort h) {
    union { uint u; float f; } o; o.u = ((uint)h) << 16;
    return o.f;
}

// async global->LDS, 16B per lane. lds ptr wave-uniform; HW scatters lane*16.
__device__ __forceinline__ void async_copy16(void* lds_uniform, const void* gaddr) {
    __builtin_amdgcn_global_load_lds(
        (const __attribute__((address_space(1))) void*)gaddr,
        (__attribute__((address_space(3))) void*)lds_uniform,
        16, 0, 0);
}

#define BARRIER() asm volatile("s_barrier" ::: "memory")
#define LGKM0()   do { asm volatile("s_waitcnt lgkmcnt(0)" ::: "memory"); \
                       __builtin_amdgcn_sched_barrier(0); } while (0)
#define LGKM_HINT() asm volatile("s_waitcnt lgkmcnt(8)" ::: "memory")
#define VMCNT(n)  asm volatile("s_waitcnt vmcnt(" #n ")" ::: "memory")

// ---------------------------------------------------------------------------
// 256x256 8-phase GEMM template. BK=64, 2 K-tiles/iter, 8 waves (2M x 4N),
// 128KB dynamic LDS (2 dbuf x (A 32KB + B 32KB)), global_load_lds staging
// with source-side chunk-XOR swizzle (slot = c ^ (row&7); 0 conflicts, R3).
// MODE 0: qkv (bias + Q/K/V split, bf16 out). MODE 1: score (bf16 out).
// MODE 2: pv (fp32 out).
// ---------------------------------------------------------------------------
template<int MODE, int KT>
__global__ __launch_bounds__(512, 2) void gemm8(
    const ushort* __restrict__ A, const ushort* __restrict__ B,
    const float* __restrict__ bias,
    void* __restrict__ out0, void* __restrict__ out1, void* __restrict__ out2,
    int lda, int ldb)
{
    extern __shared__ __align__(16) ushort lds[];
    const int tid  = threadIdx.x;
    const int w    = tid >> 6, lane = tid & 63;
    const int wr   = w >> 2,  wc   = w & 3;      // wave row(0-1) / col(0-3)
    const int lr   = lane & 15, kg = lane >> 4;  // frag row, k-chunk group
    const int srow = lane >> 3;                  // staging: row within 8-row chunk
    const int scc  = (lane & 7) ^ srow;          // staging: swizzled src chunk

    const int m0 = blockIdx.x * 256, n0 = blockIdx.y * 256;
    const ushort* Abase;
    const ushort* Bbase;
    if (MODE == 0) {
        Abase = A + (size_t)m0 * lda;
        Bbase = B + (size_t)n0 * ldb;
    } else if (MODE == 1) {
        const int b = blockIdx.z;
        Abase = A + ((size_t)(b * SEQ + m0)) * lda;
        Bbase = B + ((size_t)(b * SEQ + n0)) * ldb;
    } else {
        const int b = blockIdx.z;
        Abase = A + (size_t)b * SEQ * SEQ + (size_t)m0 * lda;
        Bbase = B + (size_t)b * DMODEL * SEQ + (size_t)n0 * ldb;
    }

    // LDS layout (ushort units): buf0 A @0, buf0 B @16384, buf1 A @32768, buf1 B @49152
    const ushort* At[2] = { lds,         lds + 32768 };
    const ushort* Bt[2] = { lds + 16384, lds + 49152 };

    // Stage one half-tile (16KB): 2 gload_lds per thread. A halves: alpha = rows
    // [0,64)u[128,192) (the mh=0 rows), beta = the rest. B halves by nh bands.
    #define STG(tile, mat, half) do { if ((tile) < KT) {                          \
        ushort* sb_ = lds + (((tile) & 1) ? 32768 : 0) + ((mat) ? 16384 : 0);     \
        const ushort* g_ = (mat) ? Bbase : Abase;                                 \
        const size_t ld_ = (mat) ? (size_t)ldb : (size_t)lda;                     \
        const int k0_ = (tile) << 6;                                              \
        _Pragma("unroll")                                                         \
        for (int t_ = 0; t_ < 2; ++t_) {                                          \
            const int c8_ = (mat) ? ((w & 3) + ((w >> 2) << 3) + (t_ << 4) + ((half) << 2)) \
                                  : (w + (t_ << 4) + ((half) << 3));              \
            const int row_ = (c8_ << 3) + srow;                                   \
            async_copy16(sb_ + c8_ * 512, g_ + (size_t)row_ * ld_ + k0_ + scc * 8); \
        } } } while (0)

    short8 af[4][2], bf[4][2];
    floatx4 acc[8][4] = {};

    #define LDFRAG(tp, row, c) \
        (*reinterpret_cast<const short8*>(&(tp)[((row) << 6) + ((((c) ^ ((row) & 7))) << 3)]))

    #define READ_A(bufi, mh) do {                                                 \
        _Pragma("unroll") for (int mf_ = 0; mf_ < 4; ++mf_)                       \
        _Pragma("unroll") for (int kk_ = 0; kk_ < 2; ++kk_)                       \
            af[mf_][kk_] = LDFRAG(At[bufi], wr * 128 + ((mh) * 4 + mf_) * 16 + lr, kk_ * 4 + kg); \
    } while (0)
    #define READ_B(bufi, nh) do {                                                 \
        _Pragma("unroll") for (int nf_ = 0; nf_ < 2; ++nf_)                       \
        _Pragma("unroll") for (int kk_ = 0; kk_ < 2; ++kk_)                       \
            bf[(nh) * 2 + nf_][kk_] = LDFRAG(Bt[bufi], wc * 64 + ((nh) * 2 + nf_) * 16 + lr, kk_ * 4 + kg); \
    } while (0)
    #define MFMA_Q(mh, nh) do {                                                   \
        __builtin_amdgcn_s_setprio(1);                                            \
        _Pragma("unroll") for (int mf_ = 0; mf_ < 4; ++mf_)                       \
        _Pragma("unroll") for (int nf_ = 0; nf_ < 2; ++nf_)                       \
        _Pragma("unroll") for (int kk_ = 0; kk_ < 2; ++kk_)                       \
            acc[(mh) * 4 + mf_][(nh) * 2 + nf_] = __builtin_amdgcn_mfma_f32_16x16x32_bf16( \
                af[mf_][kk_], bf[(nh) * 2 + nf_][kk_], acc[(mh) * 4 + mf_][(nh) * 2 + nf_], 0, 0, 0); \
        __builtin_amdgcn_s_setprio(0);                                            \
    } while (0)

    // Prologue: tile0 fully + tile1 {A-a, B-a, B-b}. 14 loads; vmcnt(6) -> tile0 resident.
    STG(0, 0, 0); STG(0, 1, 0); STG(0, 1, 1); STG(0, 0, 1);
    STG(1, 0, 0); STG(1, 1, 0); STG(1, 1, 1);
    VMCNT(6);
    BARRIER();

    #pragma unroll 1
    for (int it = 0; it < KT / 2; ++it) {
        const int t = 2 * it;
        const bool lastit = (it == KT / 2 - 1);
        // ---- K-tile t (buf 0) ----
        // P1
        READ_A(0, 0); READ_B(0, 0);
        STG(t + 1, 0, 1);
        LGKM_HINT();
        BARRIER(); LGKM0();
        MFMA_Q(0, 0);
        BARRIER();
        // P2
        READ_B(0, 1);
        STG(t + 2, 0, 0);
        BARRIER(); LGKM0();
        MFMA_Q(0, 1);
        BARRIER();
        // P3
        READ_A(0, 1);
        STG(t + 2, 1, 0);
        BARRIER(); LGKM0();
        MFMA_Q(1, 0);
        BARRIER();
        // P4
        STG(t + 2, 1, 1);
        BARRIER();
        MFMA_Q(1, 1);
        if (lastit) { VMCNT(0); } else { VMCNT(6); }
        BARRIER();
        // ---- K-tile t+1 (buf 1) ----
        // P5
        READ_A(1, 0); READ_B(1, 0);
        STG(t + 2, 0, 1);
        LGKM_HINT();
        BARRIER(); LGKM0();
        MFMA_Q(0, 0);
        BARRIER();
        // P6
        READ_B(1, 1);
        STG(t + 3, 0, 0);
        BARRIER(); LGKM0();
        MFMA_Q(0, 1);
        BARRIER();
        // P7
        READ_A(1, 1);
        STG(t + 3, 1, 0);
        BARRIER(); LGKM0();
        MFMA_Q(1, 0);
        BARRIER();
        // P8
        STG(t + 3, 1, 1);
        BARRIER();
        MFMA_Q(1, 1);
        VMCNT(6);
        BARRIER();
    }

    // Epilogue
    const int mrow = m0 + wr * 128, ncol = n0 + wc * 64;
    if (MODE == 0) {
        ushort* Qs = (ushort*)out0;
        ushort* Kb = (ushort*)out1;
        ushort* Vb = (ushort*)out2;
        #pragma unroll
        for (int nf = 0; nf < 4; ++nf) {
            const int e = ncol + nf * 16 + lr;
            const float bv = bias[e];
            const bool isQ = e < DMODEL, isK = !isQ && (e < 2 * DMODEL);
            ushort* dst = isQ ? Qs : (isK ? Kb : Vb);
            const int ec = isQ ? e : (isK ? e - DMODEL : e - 2 * DMODEL);
            const float mul = isQ ? SCALE : 1.0f;
            #pragma unroll
            for (int mf = 0; mf < 8; ++mf)
                #pragma unroll
                for (int r = 0; r < 4; ++r) {
                    const int m = mrow + mf * 16 + kg * 4 + r;
                    dst[(size_t)m * DMODEL + ec] = f2bf((acc[mf][nf][r] + bv) * mul);
                }
        }
    } else if (MODE == 1) {
        ushort* Sb = (ushort*)out0 + (size_t)blockIdx.z * SEQ * SEQ;
        #pragma unroll
        for (int nf = 0; nf < 4; ++nf) {
            const int n = ncol + nf * 16 + lr;
            #pragma unroll
            for (int mf = 0; mf < 8; ++mf)
                #pragma unroll
                for (int r = 0; r < 4; ++r) {
                    const int m = mrow + mf * 16 + kg * 4 + r;
                    Sb[(size_t)m * SEQ + n] = f2bf(acc[mf][nf][r]);
                }
        }
    } else {
        float* Ob = (float*)out0 + (size_t)blockIdx.z * SEQ * DMODEL;
        #pragma unroll
        for (int nf = 0; nf < 4; ++nf) {
            const int n = ncol + nf * 16 + lr;
            #pragma unroll
            for (int mf = 0; mf < 8; ++mf)
                #pragma unroll
                for (int r = 0; r < 4; ++r) {
                    const int m = mrow + mf * 16 + kg * 4 + r;
                    Ob[(size_t)m * DMODEL + n] = acc[mf][nf][r];
                }
        }
    }
    #undef STG
    #undef LDFRAG
    #undef READ_A
    #undef READ_B
    #undef MFMA_Q
}

// ---------------------------------------------------------------------------
// Kernel 0a: X fp32 -> bf16
// ---------------------------------------------------------------------------
__global__ __launch_bounds__(256) void convert_x(const float* __restrict__ X,
                                                 ushort* __restrict__ Xb) {
    const int total = (BATCH * SEQ * DMODEL) / 8;
    for (int i = blockIdx.x * 256 + threadIdx.x; i < total; i += gridDim.x * 256) {
        const float4 v0 = reinterpret_cast<const float4*>(X)[(size_t)i * 2];
        const float4 v1 = reinterpret_cast<const float4*>(X)[(size_t)i * 2 + 1];
        uint4 u;
        u.x = (uint)f2bf(v0.x) | ((uint)f2bf(v0.y) << 16);
        u.y = (uint)f2bf(v0.z) | ((uint)f2bf(v0.w) << 16);
        u.z = (uint)f2bf(v1.x) | ((uint)f2bf(v1.y) << 16);
        u.w = (uint)f2bf(v1.z) | ((uint)f2bf(v1.w) << 16);
        reinterpret_cast<uint4*>(Xb)[i] = u;
    }
}

// ---------------------------------------------------------------------------
// Kernel 0b: W [768][2304] fp32 -> Wt [2304][768] bf16 (transpose)
// ---------------------------------------------------------------------------
__global__ __launch_bounds__(256) void convert_wt(const float* __restrict__ W,
                                                  ushort* __restrict__ Wt) {
    __shared__ float tile[32][33];
    const int n0 = blockIdx.x * 32, k0 = blockIdx.y * 32;
    const int tx = threadIdx.x & 31, ty = threadIdx.x >> 5;
    #pragma unroll
    for (int i = 0; i < 32; i += 8)
        tile[ty + i][tx] = W[(size_t)(k0 + ty + i) * NQKV + n0 + tx];
    __syncthreads();
    #pragma unroll
    for (int i = 0; i < 32; i += 8)
        Wt[(size_t)(n0 + ty + i) * DMODEL + k0 + tx] = f2bf(tile[tx][ty + i]);
}

// ---------------------------------------------------------------------------
// Kernel 0c: V [b][n][d] bf16 -> Vt [b][d][n] bf16 (transpose)
// ---------------------------------------------------------------------------
__global__ __launch_bounds__(256) void transpose_v(const ushort* __restrict__ Vb,
                                                   ushort* __restrict__ Vt) {
    __shared__ ushort tile[32][33];
    const int b = blockIdx.z;
    const int n0 = blockIdx.x * 32, d0 = blockIdx.y * 32;
    const ushort* src = Vb + (size_t)b * SEQ * DMODEL;
    ushort* dst = Vt + (size_t)b * DMODEL * SEQ;
    const int tx = threadIdx.x & 31, ty = threadIdx.x >> 5;
    #pragma unroll
    for (int i = 0; i < 32; i += 8)
        tile[ty + i][tx] = src[(size_t)(n0 + ty + i) * DMODEL + d0 + tx];
    __syncthreads();
    #pragma unroll
    for (int i = 0; i < 32; i += 8)
        dst[(size_t)(d0 + ty + i) * SEQ + n0 + tx] = tile[tx][ty + i];
}

// ---------------------------------------------------------------------------
// Kernel 3: row softmax over 2048, in place, bf16. One block per row.
// ---------------------------------------------------------------------------
__global__ __launch_bounds__(256) void softmax_rows(ushort* __restrict__ S) {
    const int row = blockIdx.x;
    ushort* p = S + (size_t)row * SEQ;
    const int tid = threadIdx.x;
    const int wave = tid >> 6, lane = tid & 63;

    short8 v8 = *reinterpret_cast<const short8*>(p + tid * 8);
    float v[8];
    #pragma unroll
    for (int j = 0; j < 8; ++j) v[j] = bf2f((ushort)v8[j]);
    float mx = v[0];
    #pragma unroll
    for (int j = 1; j < 8; ++j) mx = fmaxf(mx, v[j]);
    #pragma unroll
    for (int off = 32; off >= 1; off >>= 1) mx = fmaxf(mx, __shfl_xor(mx, off));
    __shared__ float redm[4], reds[4];
    if (lane == 0) redm[wave] = mx;
    __syncthreads();
    mx = fmaxf(fmaxf(redm[0], redm[1]), fmaxf(redm[2], redm[3]));

    float e[8], s = 0.f;
    #pragma unroll
    for (int j = 0; j < 8; ++j) { e[j] = __expf(v[j] - mx); s += e[j]; }
    #pragma unroll
    for (int off = 32; off >= 1; off >>= 1) s += __shfl_xor(s, off);
    if (lane == 0) reds[wave] = s;
    __syncthreads();
    s = reds[0] + reds[1] + reds[2] + reds[3];
    float inv = 1.f / s;

    short8 o;
    #pragma unroll
    for (int j = 0; j < 8; ++j) o[j] = (short)f2bf(e[j] * inv);
    *reinterpret_cast<short8*>(p + tid * 8) = o;
}

// ---------------------------------------------------------------------------
extern "C" void kernel_launch(void* const* d_in, const int* in_sizes, int n_in,
                              void* d_out, int out_size, void* d_ws, size_t ws_size,
                              hipStream_t stream) {
    const float* X    = (const float*)d_in[0];
    const float* W    = (const float*)d_in[1];
    const float* bias = (const float*)d_in[2];
    float* Out = (float*)d_out;

    // Workspace layout (bytes), total 160 MiB:
    //   [0, 67.1M):  S  (scores)  -- aliases Xb [0,25.2M) + Wt [25.2M,28.7M),
    //                                which are dead before score_gemm runs.
    //   [67.1M ...): Q | K | V | Vt   (25.2M each)
    char* ws = (char*)d_ws;
    ushort* S  = (ushort*)ws;
    ushort* Xb = (ushort*)ws;
    ushort* Wt = (ushort*)(ws + (size_t)BATCH * SEQ * DMODEL * 2);
    ushort* Qs = (ushort*)(ws + (size_t)BATCH * SEQ * SEQ * 2);
    ushort* Kb = Qs + (size_t)BATCH * SEQ * DMODEL;
    ushort* Vb = Kb + (size_t)BATCH * SEQ * DMODEL;
    ushort* Vt = Vb + (size_t)BATCH * SEQ * DMODEL;

    const int LDSB = 131072;
    (void)hipFuncSetAttribute((const void*)gemm8<0, 12>,
                              hipFuncAttributeMaxDynamicSharedMemorySize, LDSB);
    (void)hipFuncSetAttribute((const void*)gemm8<1, 12>,
                              hipFuncAttributeMaxDynamicSharedMemorySize, LDSB);
    (void)hipFuncSetAttribute((const void*)gemm8<2, 32>,
                              hipFuncAttributeMaxDynamicSharedMemorySize, LDSB);

    convert_x<<<2048, 256, 0, stream>>>(X, Xb);
    convert_wt<<<dim3(NQKV / 32, DMODEL / 32), 256, 0, stream>>>(W, Wt);
    gemm8<0, 12><<<dim3(64, 9), 512, LDSB, stream>>>(
        Xb, Wt, bias, Qs, Kb, Vb, DMODEL, DMODEL);
    transpose_v<<<dim3(SEQ / 32, DMODEL / 32, BATCH), 256, 0, stream>>>(Vb, Vt);
    gemm8<1, 12><<<dim3(8, 8, 8), 512, LDSB, stream>>>(
        Qs, Kb, nullptr, S, nullptr, nullptr, DMODEL, DMODEL);
    softmax_rows<<<BATCH * SEQ, 256, 0, stream>>>(S);
    gemm8<2, 32><<<dim3(8, 3, 8), 512, LDSB, stream>>>(
        S, Vt, nullptr, Out, nullptr, nullptr, SEQ, SEQ);
}

// Round 5
// 258.871 us; speedup vs baseline: 1.3213x; 1.0330x over previous
//
#include <hip/hip_runtime.h>
#include <hip/hip_bf16.h>

typedef __attribute__((ext_vector_type(8))) short short8;
typedef __attribute__((ext_vector_type(4))) float floatx4;

#define BATCH 8
#define SEQ 2048
#define DMODEL 768
#define NQKV 2304
#define SCALE 0.03608439182435161f

__device__ __forceinline__ ushort f2bf(float f) {
    union { float f; uint u; } in; in.f = f;
    uint u = in.u;
    return (ushort)((u + 0x7FFFu + ((u >> 16) & 1u)) >> 16);
}
__device__ __forceinline__ float bf2f(ushort h) {
    union { uint u; float f; } o; o.u = ((uint)h) << 16;
    return o.f;
}

// async global->LDS, 16B per lane. lds ptr wave-uniform; HW scatters lane*16.
__device__ __forceinline__ void async_copy16(void* lds_uniform, const void* gaddr) {
    __builtin_amdgcn_global_load_lds(
        (const __attribute__((address_space(1))) void*)gaddr,
        (__attribute__((address_space(3))) void*)lds_uniform,
        16, 0, 0);
}

#define BARRIER() asm volatile("s_barrier" ::: "memory")
#define LGKM0()   do { asm volatile("s_waitcnt lgkmcnt(0)" ::: "memory"); \
                       __builtin_amdgcn_sched_barrier(0); } while (0)
#define LGKM_HINT() asm volatile("s_waitcnt lgkmcnt(8)" ::: "memory")
#define VMCNT(n)  asm volatile("s_waitcnt vmcnt(" #n ")" ::: "memory")

// ---------------------------------------------------------------------------
// 256x256 8-phase GEMM template. BK=64, 2 K-tiles/iter, 8 waves (2M x 4N),
// 128KB dynamic LDS (2 dbuf x (A 32KB + B 32KB)), global_load_lds staging
// with source-side chunk-XOR swizzle (slot = c ^ (row&7); 0 conflicts, R3).
// MODE 0: qkv (bias + Q/K/V split, bf16 out). MODE 1: score (bf16 out).
// MODE 2: pv (fp32 out).
// Epilogue (R5): per-wave LDS transpose -> dense coalesced 16B stores.
// ---------------------------------------------------------------------------
template<int MODE, int KT>
__global__ __launch_bounds__(512, 2) void gemm8(
    const ushort* __restrict__ A, const ushort* __restrict__ B,
    const float* __restrict__ bias,
    void* __restrict__ out0, void* __restrict__ out1, void* __restrict__ out2,
    int lda, int ldb)
{
    extern __shared__ __align__(16) ushort lds[];
    const int tid  = threadIdx.x;
    const int w    = tid >> 6, lane = tid & 63;
    const int wr   = w >> 2,  wc   = w & 3;      // wave row(0-1) / col(0-3)
    const int lr   = lane & 15, kg = lane >> 4;  // frag row, k-chunk group
    const int srow = lane >> 3;                  // staging: row within 8-row chunk
    const int scc  = (lane & 7) ^ srow;          // staging: swizzled src chunk

    const int m0 = blockIdx.x * 256, n0 = blockIdx.y * 256;
    const ushort* Abase;
    const ushort* Bbase;
    if (MODE == 0) {
        Abase = A + (size_t)m0 * lda;
        Bbase = B + (size_t)n0 * ldb;
    } else if (MODE == 1) {
        const int b = blockIdx.z;
        Abase = A + ((size_t)(b * SEQ + m0)) * lda;
        Bbase = B + ((size_t)(b * SEQ + n0)) * ldb;
    } else {
        const int b = blockIdx.z;
        Abase = A + (size_t)b * SEQ * SEQ + (size_t)m0 * lda;
        Bbase = B + (size_t)b * DMODEL * SEQ + (size_t)n0 * ldb;
    }

    // LDS layout (ushort units): buf0 A @0, buf0 B @16384, buf1 A @32768, buf1 B @49152
    const ushort* At[2] = { lds,         lds + 32768 };
    const ushort* Bt[2] = { lds + 16384, lds + 49152 };

    // Stage one half-tile (16KB): 2 gload_lds per thread. A halves: alpha = rows
    // [0,64)u[128,192) (the mh=0 rows), beta = the rest. B halves by nh bands.
    #define STG(tile, mat, half) do { if ((tile) < KT) {                          \
        ushort* sb_ = lds + (((tile) & 1) ? 32768 : 0) + ((mat) ? 16384 : 0);     \
        const ushort* g_ = (mat) ? Bbase : Abase;                                 \
        const size_t ld_ = (mat) ? (size_t)ldb : (size_t)lda;                     \
        const int k0_ = (tile) << 6;                                              \
        _Pragma("unroll")                                                         \
        for (int t_ = 0; t_ < 2; ++t_) {                                          \
            const int c8_ = (mat) ? ((w & 3) + ((w >> 2) << 3) + (t_ << 4) + ((half) << 2)) \
                                  : (w + (t_ << 4) + ((half) << 3));              \
            const int row_ = (c8_ << 3) + srow;                                   \
            async_copy16(sb_ + c8_ * 512, g_ + (size_t)row_ * ld_ + k0_ + scc * 8); \
        } } } while (0)

    short8 af[4][2], bf[4][2];
    floatx4 acc[8][4] = {};

    #define LDFRAG(tp, row, c) \
        (*reinterpret_cast<const short8*>(&(tp)[((row) << 6) + ((((c) ^ ((row) & 7))) << 3)]))

    #define READ_A(bufi, mh) do {                                                 \
        _Pragma("unroll") for (int mf_ = 0; mf_ < 4; ++mf_)                       \
        _Pragma("unroll") for (int kk_ = 0; kk_ < 2; ++kk_)                       \
            af[mf_][kk_] = LDFRAG(At[bufi], wr * 128 + ((mh) * 4 + mf_) * 16 + lr, kk_ * 4 + kg); \
    } while (0)
    #define READ_B(bufi, nh) do {                                                 \
        _Pragma("unroll") for (int nf_ = 0; nf_ < 2; ++nf_)                       \
        _Pragma("unroll") for (int kk_ = 0; kk_ < 2; ++kk_)                       \
            bf[(nh) * 2 + nf_][kk_] = LDFRAG(Bt[bufi], wc * 64 + ((nh) * 2 + nf_) * 16 + lr, kk_ * 4 + kg); \
    } while (0)
    #define MFMA_Q(mh, nh) do {                                                   \
        __builtin_amdgcn_s_setprio(1);                                            \
        _Pragma("unroll") for (int mf_ = 0; mf_ < 4; ++mf_)                       \
        _Pragma("unroll") for (int nf_ = 0; nf_ < 2; ++nf_)                       \
        _Pragma("unroll") for (int kk_ = 0; kk_ < 2; ++kk_)                       \
            acc[(mh) * 4 + mf_][(nh) * 2 + nf_] = __builtin_amdgcn_mfma_f32_16x16x32_bf16( \
                af[mf_][kk_], bf[(nh) * 2 + nf_][kk_], acc[(mh) * 4 + mf_][(nh) * 2 + nf_], 0, 0, 0); \
        __builtin_amdgcn_s_setprio(0);                                            \
    } while (0)

    // Prologue: tile0 fully + tile1 {A-a, B-a, B-b}. 14 loads; vmcnt(6) -> tile0 resident.
    STG(0, 0, 0); STG(0, 1, 0); STG(0, 1, 1); STG(0, 0, 1);
    STG(1, 0, 0); STG(1, 1, 0); STG(1, 1, 1);
    VMCNT(6);
    BARRIER();

    #pragma unroll 1
    for (int it = 0; it < KT / 2; ++it) {
        const int t = 2 * it;
        const bool lastit = (it == KT / 2 - 1);
        // ---- K-tile t (buf 0) ----
        // P1
        READ_A(0, 0); READ_B(0, 0);
        STG(t + 1, 0, 1);
        LGKM_HINT();
        BARRIER(); LGKM0();
        MFMA_Q(0, 0);
        BARRIER();
        // P2
        READ_B(0, 1);
        STG(t + 2, 0, 0);
        BARRIER(); LGKM0();
        MFMA_Q(0, 1);
        BARRIER();
        // P3
        READ_A(0, 1);
        STG(t + 2, 1, 0);
        BARRIER(); LGKM0();
        MFMA_Q(1, 0);
        BARRIER();
        // P4
        STG(t + 2, 1, 1);
        BARRIER();
        MFMA_Q(1, 1);
        if (lastit) { VMCNT(0); } else { VMCNT(6); }
        BARRIER();
        // ---- K-tile t+1 (buf 1) ----
        // P5
        READ_A(1, 0); READ_B(1, 0);
        STG(t + 2, 0, 1);
        LGKM_HINT();
        BARRIER(); LGKM0();
        MFMA_Q(0, 0);
        BARRIER();
        // P6
        READ_B(1, 1);
        STG(t + 3, 0, 0);
        BARRIER(); LGKM0();
        MFMA_Q(0, 1);
        BARRIER();
        // P7
        READ_A(1, 1);
        STG(t + 3, 1, 0);
        BARRIER(); LGKM0();
        MFMA_Q(1, 0);
        BARRIER();
        // P8
        STG(t + 3, 1, 1);
        BARRIER();
        MFMA_Q(1, 1);
        VMCNT(6);
        BARRIER();
    }

    // ---- Epilogue (R5): per-wave LDS transpose -> dense coalesced stores ----
    // Safe: after final P8 barrier all waves are past every staging read and
    // VMCNT(0) (last iter P4) drained all global_load_lds writes.
    // Per-wave private scratch: [32 cols][stride 68 rows] fp32 = 8704 B.
    {
        float* scr = reinterpret_cast<float*>(reinterpret_cast<char*>(lds) + (size_t)w * 9216);
        const int mrow = m0 + wr * 128;
        const int ncol = n0 + wc * 64;
        #pragma unroll
        for (int mh = 0; mh < 2; ++mh) {
            #pragma unroll
            for (int np = 0; np < 2; ++np) {
                // Transpose-in: ds_write_b128, col-major (4 consecutive rows per write).
                #pragma unroll
                for (int mf = 0; mf < 4; ++mf)
                    #pragma unroll
                    for (int nf2 = 0; nf2 < 2; ++nf2) {
                        const floatx4 v = acc[mh * 4 + mf][np * 2 + nf2];
                        *reinterpret_cast<floatx4*>(
                            &scr[(nf2 * 16 + lr) * 68 + mf * 16 + kg * 4]) = v;
                    }
                asm volatile("s_waitcnt lgkmcnt(0)" ::: "memory");
                __builtin_amdgcn_sched_barrier(0);

                if (MODE == 2) {
                    float* Ob = (float*)out0 + (size_t)blockIdx.z * SEQ * DMODEL;
                    const int c4 = (lane & 7) * 4;
                    #pragma unroll
                    for (int p = 0; p < 8; ++p) {
                        const int row = p * 8 + (lane >> 3);
                        float4 v;
                        v.x = scr[(c4 + 0) * 68 + row];
                        v.y = scr[(c4 + 1) * 68 + row];
                        v.z = scr[(c4 + 2) * 68 + row];
                        v.w = scr[(c4 + 3) * 68 + row];
                        *reinterpret_cast<float4*>(
                            &Ob[(size_t)(mrow + mh * 64 + row) * DMODEL + ncol + np * 32 + c4]) = v;
                    }
                } else {
                    const int c8 = (lane & 3) * 8;
                    const int e0 = ncol + np * 32 + c8;
                    ushort* dst; int ec; float mul;
                    float bs[8] = {0, 0, 0, 0, 0, 0, 0, 0};
                    if (MODE == 0) {
                        const bool isQ = e0 < DMODEL, isK = !isQ && (e0 < 2 * DMODEL);
                        dst = isQ ? (ushort*)out0 : (isK ? (ushort*)out1 : (ushort*)out2);
                        ec  = isQ ? e0 : (isK ? e0 - DMODEL : e0 - 2 * DMODEL);
                        mul = isQ ? SCALE : 1.0f;
                        const float4 b0 = *reinterpret_cast<const float4*>(&bias[e0]);
                        const float4 b1 = *reinterpret_cast<const float4*>(&bias[e0 + 4]);
                        bs[0] = b0.x * mul; bs[1] = b0.y * mul;
                        bs[2] = b0.z * mul; bs[3] = b0.w * mul;
                        bs[4] = b1.x * mul; bs[5] = b1.y * mul;
                        bs[6] = b1.z * mul; bs[7] = b1.w * mul;
                    } else {
                        dst = (ushort*)out0 + (size_t)blockIdx.z * SEQ * SEQ;
                        ec = e0; mul = 1.0f;
                    }
                    const size_t ostride = (MODE == 0) ? (size_t)DMODEL : (size_t)SEQ;
                    #pragma unroll
                    for (int p = 0; p < 4; ++p) {
                        const int row = p * 16 + (lane >> 2);
                        short8 o;
                        #pragma unroll
                        for (int j = 0; j < 8; ++j) {
                            const float f = scr[(c8 + j) * 68 + row] * mul + bs[j];
                            o[j] = (short)f2bf(f);
                        }
                        *reinterpret_cast<short8*>(
                            &dst[(size_t)(mrow + mh * 64 + row) * ostride + ec]) = o;
                    }
                }
                // Reads must complete before this wave rewrites its region.
                asm volatile("s_waitcnt lgkmcnt(0)" ::: "memory");
                __builtin_amdgcn_sched_barrier(0);
            }
        }
    }
    #undef STG
    #undef LDFRAG
    #undef READ_A
    #undef READ_B
    #undef MFMA_Q
}

// ---------------------------------------------------------------------------
// Kernel 0a: X fp32 -> bf16
// ---------------------------------------------------------------------------
__global__ __launch_bounds__(256) void convert_x(const float* __restrict__ X,
                                                 ushort* __restrict__ Xb) {
    const int total = (BATCH * SEQ * DMODEL) / 8;
    for (int i = blockIdx.x * 256 + threadIdx.x; i < total; i += gridDim.x * 256) {
        const float4 v0 = reinterpret_cast<const float4*>(X)[(size_t)i * 2];
        const float4 v1 = reinterpret_cast<const float4*>(X)[(size_t)i * 2 + 1];
        uint4 u;
        u.x = (uint)f2bf(v0.x) | ((uint)f2bf(v0.y) << 16);
        u.y = (uint)f2bf(v0.z) | ((uint)f2bf(v0.w) << 16);
        u.z = (uint)f2bf(v1.x) | ((uint)f2bf(v1.y) << 16);
        u.w = (uint)f2bf(v1.z) | ((uint)f2bf(v1.w) << 16);
        reinterpret_cast<uint4*>(Xb)[i] = u;
    }
}

// ---------------------------------------------------------------------------
// Kernel 0b: W [768][2304] fp32 -> Wt [2304][768] bf16 (transpose)
// ---------------------------------------------------------------------------
__global__ __launch_bounds__(256) void convert_wt(const float* __restrict__ W,
                                                  ushort* __restrict__ Wt) {
    __shared__ float tile[32][33];
    const int n0 = blockIdx.x * 32, k0 = blockIdx.y * 32;
    const int tx = threadIdx.x & 31, ty = threadIdx.x >> 5;
    #pragma unroll
    for (int i = 0; i < 32; i += 8)
        tile[ty + i][tx] = W[(size_t)(k0 + ty + i) * NQKV + n0 + tx];
    __syncthreads();
    #pragma unroll
    for (int i = 0; i < 32; i += 8)
        Wt[(size_t)(n0 + ty + i) * DMODEL + k0 + tx] = f2bf(tile[tx][ty + i]);
}

// ---------------------------------------------------------------------------
// Kernel 0c: V [b][n][d] bf16 -> Vt [b][d][n] bf16 (transpose)
// ---------------------------------------------------------------------------
__global__ __launch_bounds__(256) void transpose_v(const ushort* __restrict__ Vb,
                                                   ushort* __restrict__ Vt) {
    __shared__ ushort tile[32][33];
    const int b = blockIdx.z;
    const int n0 = blockIdx.x * 32, d0 = blockIdx.y * 32;
    const ushort* src = Vb + (size_t)b * SEQ * DMODEL;
    ushort* dst = Vt + (size_t)b * DMODEL * SEQ;
    const int tx = threadIdx.x & 31, ty = threadIdx.x >> 5;
    #pragma unroll
    for (int i = 0; i < 32; i += 8)
        tile[ty + i][tx] = src[(size_t)(n0 + ty + i) * DMODEL + d0 + tx];
    __syncthreads();
    #pragma unroll
    for (int i = 0; i < 32; i += 8)
        dst[(size_t)(d0 + ty + i) * SEQ + n0 + tx] = tile[tx][ty + i];
}

// ---------------------------------------------------------------------------
// Kernel 3: row softmax over 2048, in place, bf16. One block per row.
// ---------------------------------------------------------------------------
__global__ __launch_bounds__(256) void softmax_rows(ushort* __restrict__ S) {
    const int row = blockIdx.x;
    ushort* p = S + (size_t)row * SEQ;
    const int tid = threadIdx.x;
    const int wave = tid >> 6, lane = tid & 63;

    short8 v8 = *reinterpret_cast<const short8*>(p + tid * 8);
    float v[8];
    #pragma unroll
    for (int j = 0; j < 8; ++j) v[j] = bf2f((ushort)v8[j]);
    float mx = v[0];
    #pragma unroll
    for (int j = 1; j < 8; ++j) mx = fmaxf(mx, v[j]);
    #pragma unroll
    for (int off = 32; off >= 1; off >>= 1) mx = fmaxf(mx, __shfl_xor(mx, off));
    __shared__ float redm[4], reds[4];
    if (lane == 0) redm[wave] = mx;
    __syncthreads();
    mx = fmaxf(fmaxf(redm[0], redm[1]), fmaxf(redm[2], redm[3]));

    float e[8], s = 0.f;
    #pragma unroll
    for (int j = 0; j < 8; ++j) { e[j] = __expf(v[j] - mx); s += e[j]; }
    #pragma unroll
    for (int off = 32; off >= 1; off >>= 1) s += __shfl_xor(s, off);
    if (lane == 0) reds[wave] = s;
    __syncthreads();
    s = reds[0] + reds[1] + reds[2] + reds[3];
    float inv = 1.f / s;

    short8 o;
    #pragma unroll
    for (int j = 0; j < 8; ++j) o[j] = (short)f2bf(e[j] * inv);
    *reinterpret_cast<short8*>(p + tid * 8) = o;
}

// ---------------------------------------------------------------------------
extern "C" void kernel_launch(void* const* d_in, const int* in_sizes, int n_in,
                              void* d_out, int out_size, void* d_ws, size_t ws_size,
                              hipStream_t stream) {
    const float* X    = (const float*)d_in[0];
    const float* W    = (const float*)d_in[1];
    const float* bias = (const float*)d_in[2];
    float* Out = (float*)d_out;

    // Workspace layout (bytes), total 160 MiB:
    //   [0, 67.1M):  S  (scores)  -- aliases Xb [0,25.2M) + Wt [25.2M,28.7M),
    //                                which are dead before score_gemm runs.
    //   [67.1M ...): Q | K | V | Vt   (25.2M each)
    char* ws = (char*)d_ws;
    ushort* S  = (ushort*)ws;
    ushort* Xb = (ushort*)ws;
    ushort* Wt = (ushort*)(ws + (size_t)BATCH * SEQ * DMODEL * 2);
    ushort* Qs = (ushort*)(ws + (size_t)BATCH * SEQ * SEQ * 2);
    ushort* Kb = Qs + (size_t)BATCH * SEQ * DMODEL;
    ushort* Vb = Kb + (size_t)BATCH * SEQ * DMODEL;
    ushort* Vt = Vb + (size_t)BATCH * SEQ * DMODEL;

    const int LDSB = 131072;
    (void)hipFuncSetAttribute((const void*)gemm8<0, 12>,
                              hipFuncAttributeMaxDynamicSharedMemorySize, LDSB);
    (void)hipFuncSetAttribute((const void*)gemm8<1, 12>,
                              hipFuncAttributeMaxDynamicSharedMemorySize, LDSB);
    (void)hipFuncSetAttribute((const void*)gemm8<2, 32>,
                              hipFuncAttributeMaxDynamicSharedMemorySize, LDSB);

    convert_x<<<2048, 256, 0, stream>>>(X, Xb);
    convert_wt<<<dim3(NQKV / 32, DMODEL / 32), 256, 0, stream>>>(W, Wt);
    gemm8<0, 12><<<dim3(64, 9), 512, LDSB, stream>>>(
        Xb, Wt, bias, Qs, Kb, Vb, DMODEL, DMODEL);
    transpose_v<<<dim3(SEQ / 32, DMODEL / 32, BATCH), 256, 0, stream>>>(Vb, Vt);
    gemm8<1, 12><<<dim3(8, 8, 8), 512, LDSB, stream>>>(
        Qs, Kb, nullptr, S, nullptr, nullptr, DMODEL, DMODEL);
    softmax_rows<<<BATCH * SEQ, 256, 0, stream>>>(S);
    gemm8<2, 32><<<dim3(8, 3, 8), 512, LDSB, stream>>>(
        S, Vt, nullptr, Out, nullptr, nullptr, SEQ, SEQ);
}

// Round 6
// 243.908 us; speedup vs baseline: 1.4024x; 1.0613x over previous
//
#include <hip/hip_runtime.h>
#include <hip/hip_bf16.h>

typedef __attribute__((ext_vector_type(8))) short short8;
typedef __attribute__((ext_vector_type(4))) float floatx4;

#define BATCH 8
#define SEQ 2048
#define DMODEL 768
#define NQKV 2304
#define SCALE 0.03608439182435161f

__device__ __forceinline__ ushort f2bf(float f) {
    union { float f; uint u; } in; in.f = f;
    uint u = in.u;
    return (ushort)((u + 0x7FFFu + ((u >> 16) & 1u)) >> 16);
}
__device__ __forceinline__ float bf2f(ushort h) {
    union { uint u; float f; } o; o.u = ((uint)h) << 16;
    return o.f;
}

// async global->LDS, 16B per lane. lds ptr wave-uniform; HW scatters lane*16.
__device__ __forceinline__ void async_copy16(void* lds_uniform, const void* gaddr) {
    __builtin_amdgcn_global_load_lds(
        (const __attribute__((address_space(1))) void*)gaddr,
        (__attribute__((address_space(3))) void*)lds_uniform,
        16, 0, 0);
}

#define BARRIER() asm volatile("s_barrier" ::: "memory")
#define LGKM0()   do { asm volatile("s_waitcnt lgkmcnt(0)" ::: "memory"); \
                       __builtin_amdgcn_sched_barrier(0); } while (0)
#define LGKM_HINT() asm volatile("s_waitcnt lgkmcnt(8)" ::: "memory")
#define VMCNT(n)  asm volatile("s_waitcnt vmcnt(" #n ")" ::: "memory")

// ---------------------------------------------------------------------------
// 256x256 8-phase GEMM template. BK=64, 2 K-tiles/iter, 8 waves (2M x 4N),
// 128KB dynamic LDS (2 dbuf x (A 32KB + B 32KB)), global_load_lds staging
// with source-side chunk-XOR swizzle (slot = c ^ (row&7); 0 conflicts, R3).
// MODE 0: qkv (bias; Q/K row-major bf16; V stored TRANSPOSED to Vt).
// MODE 1: score (bf16 out). MODE 2: pv (fp32 out).
// Epilogue (R6): row-major per-wave scratch [64][36] fp32 — scalar ds_write
// (2-way, free) + contiguous ds_read_b128 (8 lanes/quad = dense) -> dense
// coalesced global stores. V-quadrants bypass LDS (fragment-native 8B stores).
// ---------------------------------------------------------------------------
template<int MODE, int KT>
__global__ __launch_bounds__(512, 2) void gemm8(
    const ushort* __restrict__ A, const ushort* __restrict__ B,
    const float* __restrict__ bias,
    void* __restrict__ out0, void* __restrict__ out1, void* __restrict__ out2,
    int lda, int ldb)
{
    extern __shared__ __align__(16) ushort lds[];
    const int tid  = threadIdx.x;
    const int w    = tid >> 6, lane = tid & 63;
    const int wr   = w >> 2,  wc   = w & 3;      // wave row(0-1) / col(0-3)
    const int lr   = lane & 15, kg = lane >> 4;  // frag row, k-chunk group
    const int srow = lane >> 3;                  // staging: row within 8-row chunk
    const int scc  = (lane & 7) ^ srow;          // staging: swizzled src chunk

    const int m0 = blockIdx.x * 256, n0 = blockIdx.y * 256;
    const ushort* Abase;
    const ushort* Bbase;
    if (MODE == 0) {
        Abase = A + (size_t)m0 * lda;
        Bbase = B + (size_t)n0 * ldb;
    } else if (MODE == 1) {
        const int b = blockIdx.z;
        Abase = A + ((size_t)(b * SEQ + m0)) * lda;
        Bbase = B + ((size_t)(b * SEQ + n0)) * ldb;
    } else {
        const int b = blockIdx.z;
        Abase = A + (size_t)b * SEQ * SEQ + (size_t)m0 * lda;
        Bbase = B + (size_t)b * DMODEL * SEQ + (size_t)n0 * ldb;
    }

    // LDS layout (ushort units): buf0 A @0, buf0 B @16384, buf1 A @32768, buf1 B @49152
    const ushort* At[2] = { lds,         lds + 32768 };
    const ushort* Bt[2] = { lds + 16384, lds + 49152 };

    // Stage one half-tile (16KB): 2 gload_lds per thread. A halves: alpha = rows
    // [0,64)u[128,192) (the mh=0 rows), beta = the rest. B halves by nh bands.
    #define STG(tile, mat, half) do { if ((tile) < KT) {                          \
        ushort* sb_ = lds + (((tile) & 1) ? 32768 : 0) + ((mat) ? 16384 : 0);     \
        const ushort* g_ = (mat) ? Bbase : Abase;                                 \
        const size_t ld_ = (mat) ? (size_t)ldb : (size_t)lda;                     \
        const int k0_ = (tile) << 6;                                              \
        _Pragma("unroll")                                                         \
        for (int t_ = 0; t_ < 2; ++t_) {                                          \
            const int c8_ = (mat) ? ((w & 3) + ((w >> 2) << 3) + (t_ << 4) + ((half) << 2)) \
                                  : (w + (t_ << 4) + ((half) << 3));              \
            const int row_ = (c8_ << 3) + srow;                                   \
            async_copy16(sb_ + c8_ * 512, g_ + (size_t)row_ * ld_ + k0_ + scc * 8); \
        } } } while (0)

    short8 af[4][2], bf[4][2];
    floatx4 acc[8][4] = {};

    #define LDFRAG(tp, row, c) \
        (*reinterpret_cast<const short8*>(&(tp)[((row) << 6) + ((((c) ^ ((row) & 7))) << 3)]))

    #define READ_A(bufi, mh) do {                                                 \
        _Pragma("unroll") for (int mf_ = 0; mf_ < 4; ++mf_)                       \
        _Pragma("unroll") for (int kk_ = 0; kk_ < 2; ++kk_)                       \
            af[mf_][kk_] = LDFRAG(At[bufi], wr * 128 + ((mh) * 4 + mf_) * 16 + lr, kk_ * 4 + kg); \
    } while (0)
    #define READ_B(bufi, nh) do {                                                 \
        _Pragma("unroll") for (int nf_ = 0; nf_ < 2; ++nf_)                       \
        _Pragma("unroll") for (int kk_ = 0; kk_ < 2; ++kk_)                       \
            bf[(nh) * 2 + nf_][kk_] = LDFRAG(Bt[bufi], wc * 64 + ((nh) * 2 + nf_) * 16 + lr, kk_ * 4 + kg); \
    } while (0)
    #define MFMA_Q(mh, nh) do {                                                   \
        __builtin_amdgcn_s_setprio(1);                                            \
        _Pragma("unroll") for (int mf_ = 0; mf_ < 4; ++mf_)                       \
        _Pragma("unroll") for (int nf_ = 0; nf_ < 2; ++nf_)                       \
        _Pragma("unroll") for (int kk_ = 0; kk_ < 2; ++kk_)                       \
            acc[(mh) * 4 + mf_][(nh) * 2 + nf_] = __builtin_amdgcn_mfma_f32_16x16x32_bf16( \
                af[mf_][kk_], bf[(nh) * 2 + nf_][kk_], acc[(mh) * 4 + mf_][(nh) * 2 + nf_], 0, 0, 0); \
        __builtin_amdgcn_s_setprio(0);                                            \
    } while (0)

    // Prologue: tile0 fully + tile1 {A-a, B-a, B-b}. 14 loads; vmcnt(6) -> tile0 resident.
    STG(0, 0, 0); STG(0, 1, 0); STG(0, 1, 1); STG(0, 0, 1);
    STG(1, 0, 0); STG(1, 1, 0); STG(1, 1, 1);
    VMCNT(6);
    BARRIER();

    #pragma unroll 1
    for (int it = 0; it < KT / 2; ++it) {
        const int t = 2 * it;
        const bool lastit = (it == KT / 2 - 1);
        // ---- K-tile t (buf 0) ----
        // P1
        READ_A(0, 0); READ_B(0, 0);
        STG(t + 1, 0, 1);
        LGKM_HINT();
        BARRIER(); LGKM0();
        MFMA_Q(0, 0);
        BARRIER();
        // P2
        READ_B(0, 1);
        STG(t + 2, 0, 0);
        BARRIER(); LGKM0();
        MFMA_Q(0, 1);
        BARRIER();
        // P3
        READ_A(0, 1);
        STG(t + 2, 1, 0);
        BARRIER(); LGKM0();
        MFMA_Q(1, 0);
        BARRIER();
        // P4
        STG(t + 2, 1, 1);
        BARRIER();
        MFMA_Q(1, 1);
        if (lastit) { VMCNT(0); } else { VMCNT(6); }
        BARRIER();
        // ---- K-tile t+1 (buf 1) ----
        // P5
        READ_A(1, 0); READ_B(1, 0);
        STG(t + 2, 0, 1);
        LGKM_HINT();
        BARRIER(); LGKM0();
        MFMA_Q(0, 0);
        BARRIER();
        // P6
        READ_B(1, 1);
        STG(t + 3, 0, 0);
        BARRIER(); LGKM0();
        MFMA_Q(0, 1);
        BARRIER();
        // P7
        READ_A(1, 1);
        STG(t + 3, 1, 0);
        BARRIER(); LGKM0();
        MFMA_Q(1, 0);
        BARRIER();
        // P8
        STG(t + 3, 1, 1);
        BARRIER();
        MFMA_Q(1, 1);
        VMCNT(6);
        BARRIER();
    }

    // ---- Epilogue (R6) ----
    // Safe: after final P8 barrier all waves are past every staging read and
    // VMCNT(0) (last iter P4) drained all global_load_lds writes.
    const int mrow = m0 + wr * 128;
    const int ncol = n0 + wc * 64;

    if (MODE == 0 && blockIdx.y >= 6) {
        // V quadrant: fragment-native transposed store straight to Vt[b][d][n].
        // Per lane: 4 consecutive m (kg*4+r) for fixed d -> 8B uint2 packs.
        ushort* Vt = (ushort*)out2;
        const int bIdx = m0 >> 11;        // batch (tiles never straddle: 2048%256==0)
        const int ns0  = m0 & 2047;       // seq offset within batch
        #pragma unroll
        for (int nf = 0; nf < 4; ++nf) {
            const int e = ncol + nf * 16 + lr;        // 1536..2303
            const int d = e - 2 * DMODEL;
            const float bv = bias[e];
            ushort* vrow = Vt + ((size_t)bIdx * DMODEL + d) * SEQ + ns0;
            #pragma unroll
            for (int a = 0; a < 8; ++a) {
                const floatx4 v = acc[a][nf];
                uint2 u;
                u.x = (uint)f2bf(v[0] + bv) | ((uint)f2bf(v[1] + bv) << 16);
                u.y = (uint)f2bf(v[2] + bv) | ((uint)f2bf(v[3] + bv) << 16);
                *reinterpret_cast<uint2*>(vrow + wr * 128 + a * 16 + kg * 4) = u;
            }
        }
    } else {
        // Row-major per-wave scratch [64 rows][stride 36] fp32 = 9216 B.
        // Write: scalar ds_write_b32, bank = lr + 16(kg&1) -> 2-way (free).
        // Read: contiguous ds_read_b128, quad = (rr+2s+sel)%8 -> 8 lanes/quad (dense).
        float* scr = reinterpret_cast<float*>(reinterpret_cast<char*>(lds) + (size_t)w * 9216);
        #pragma unroll
        for (int mh = 0; mh < 2; ++mh) {
            #pragma unroll
            for (int np = 0; np < 2; ++np) {
                #pragma unroll
                for (int mf = 0; mf < 4; ++mf)
                    #pragma unroll
                    for (int nf2 = 0; nf2 < 2; ++nf2) {
                        const floatx4 v = acc[mh * 4 + mf][np * 2 + nf2];
                        #pragma unroll
                        for (int r = 0; r < 4; ++r)
                            scr[(mf * 16 + kg * 4 + r) * 36 + nf2 * 16 + lr] = v[r];
                    }
                asm volatile("s_waitcnt lgkmcnt(0)" ::: "memory");
                __builtin_amdgcn_sched_barrier(0);

                if (MODE == 2) {
                    float* Ob = (float*)out0 + (size_t)blockIdx.z * SEQ * DMODEL;
                    const int c4 = (lane & 7) * 4;
                    #pragma unroll
                    for (int p = 0; p < 8; ++p) {
                        const int row = p * 8 + (lane >> 3);
                        const float4 v = *reinterpret_cast<const float4*>(&scr[row * 36 + c4]);
                        *reinterpret_cast<float4*>(
                            &Ob[(size_t)(mrow + mh * 64 + row) * DMODEL + ncol + np * 32 + c4]) = v;
                    }
                } else {
                    const int c8 = (lane & 3) * 8;
                    const int e0 = ncol + np * 32 + c8;
                    ushort* dst; int ec; float mul;
                    float bs[8] = {0, 0, 0, 0, 0, 0, 0, 0};
                    if (MODE == 0) {
                        const bool isQ = e0 < DMODEL;
                        dst = isQ ? (ushort*)out0 : (ushort*)out1;
                        ec  = isQ ? e0 : e0 - DMODEL;
                        mul = isQ ? SCALE : 1.0f;
                        const float4 b0 = *reinterpret_cast<const float4*>(&bias[e0]);
                        const float4 b1 = *reinterpret_cast<const float4*>(&bias[e0 + 4]);
                        bs[0] = b0.x * mul; bs[1] = b0.y * mul;
                        bs[2] = b0.z * mul; bs[3] = b0.w * mul;
                        bs[4] = b1.x * mul; bs[5] = b1.y * mul;
                        bs[6] = b1.z * mul; bs[7] = b1.w * mul;
                    } else {
                        dst = (ushort*)out0 + (size_t)blockIdx.z * SEQ * SEQ;
                        ec = e0; mul = 1.0f;
                    }
                    const size_t ostride = (MODE == 0) ? (size_t)DMODEL : (size_t)SEQ;
                    #pragma unroll
                    for (int p = 0; p < 4; ++p) {
                        const int row = p * 16 + (lane >> 2);
                        const float4 lo = *reinterpret_cast<const float4*>(&scr[row * 36 + c8]);
                        const float4 hi = *reinterpret_cast<const float4*>(&scr[row * 36 + c8 + 4]);
                        short8 o;
                        o[0] = (short)f2bf(lo.x * mul + bs[0]);
                        o[1] = (short)f2bf(lo.y * mul + bs[1]);
                        o[2] = (short)f2bf(lo.z * mul + bs[2]);
                        o[3] = (short)f2bf(lo.w * mul + bs[3]);
                        o[4] = (short)f2bf(hi.x * mul + bs[4]);
                        o[5] = (short)f2bf(hi.y * mul + bs[5]);
                        o[6] = (short)f2bf(hi.z * mul + bs[6]);
                        o[7] = (short)f2bf(hi.w * mul + bs[7]);
                        *reinterpret_cast<short8*>(
                            &dst[(size_t)(mrow + mh * 64 + row) * ostride + ec]) = o;
                    }
                }
                // Reads must complete before this wave rewrites its region.
                asm volatile("s_waitcnt lgkmcnt(0)" ::: "memory");
                __builtin_amdgcn_sched_barrier(0);
            }
        }
    }
    #undef STG
    #undef LDFRAG
    #undef READ_A
    #undef READ_B
    #undef MFMA_Q
}

// ---------------------------------------------------------------------------
// Kernel 0a: X fp32 -> bf16
// ---------------------------------------------------------------------------
__global__ __launch_bounds__(256) void convert_x(const float* __restrict__ X,
                                                 ushort* __restrict__ Xb) {
    const int total = (BATCH * SEQ * DMODEL) / 8;
    for (int i = blockIdx.x * 256 + threadIdx.x; i < total; i += gridDim.x * 256) {
        const float4 v0 = reinterpret_cast<const float4*>(X)[(size_t)i * 2];
        const float4 v1 = reinterpret_cast<const float4*>(X)[(size_t)i * 2 + 1];
        uint4 u;
        u.x = (uint)f2bf(v0.x) | ((uint)f2bf(v0.y) << 16);
        u.y = (uint)f2bf(v0.z) | ((uint)f2bf(v0.w) << 16);
        u.z = (uint)f2bf(v1.x) | ((uint)f2bf(v1.y) << 16);
        u.w = (uint)f2bf(v1.z) | ((uint)f2bf(v1.w) << 16);
        reinterpret_cast<uint4*>(Xb)[i] = u;
    }
}

// ---------------------------------------------------------------------------
// Kernel 0b: W [768][2304] fp32 -> Wt [2304][768] bf16 (transpose)
// ---------------------------------------------------------------------------
__global__ __launch_bounds__(256) void convert_wt(const float* __restrict__ W,
                                                  ushort* __restrict__ Wt) {
    __shared__ float tile[32][33];
    const int n0 = blockIdx.x * 32, k0 = blockIdx.y * 32;
    const int tx = threadIdx.x & 31, ty = threadIdx.x >> 5;
    #pragma unroll
    for (int i = 0; i < 32; i += 8)
        tile[ty + i][tx] = W[(size_t)(k0 + ty + i) * NQKV + n0 + tx];
    __syncthreads();
    #pragma unroll
    for (int i = 0; i < 32; i += 8)
        Wt[(size_t)(n0 + ty + i) * DMODEL + k0 + tx] = f2bf(tile[tx][ty + i]);
}

// ---------------------------------------------------------------------------
// Kernel 3: row softmax over 2048, in place, bf16. One block per row.
// ---------------------------------------------------------------------------
__global__ __launch_bounds__(256) void softmax_rows(ushort* __restrict__ S) {
    const int row = blockIdx.x;
    ushort* p = S + (size_t)row * SEQ;
    const int tid = threadIdx.x;
    const int wave = tid >> 6, lane = tid & 63;

    short8 v8 = *reinterpret_cast<const short8*>(p + tid * 8);
    float v[8];
    #pragma unroll
    for (int j = 0; j < 8; ++j) v[j] = bf2f((ushort)v8[j]);
    float mx = v[0];
    #pragma unroll
    for (int j = 1; j < 8; ++j) mx = fmaxf(mx, v[j]);
    #pragma unroll
    for (int off = 32; off >= 1; off >>= 1) mx = fmaxf(mx, __shfl_xor(mx, off));
    __shared__ float redm[4], reds[4];
    if (lane == 0) redm[wave] = mx;
    __syncthreads();
    mx = fmaxf(fmaxf(redm[0], redm[1]), fmaxf(redm[2], redm[3]));

    float e[8], s = 0.f;
    #pragma unroll
    for (int j = 0; j < 8; ++j) { e[j] = __expf(v[j] - mx); s += e[j]; }
    #pragma unroll
    for (int off = 32; off >= 1; off >>= 1) s += __shfl_xor(s, off);
    if (lane == 0) reds[wave] = s;
    __syncthreads();
    s = reds[0] + reds[1] + reds[2] + reds[3];
    float inv = 1.f / s;

    short8 o;
    #pragma unroll
    for (int j = 0; j < 8; ++j) o[j] = (short)f2bf(e[j] * inv);
    *reinterpret_cast<short8*>(p + tid * 8) = o;
}

// ---------------------------------------------------------------------------
extern "C" void kernel_launch(void* const* d_in, const int* in_sizes, int n_in,
                              void* d_out, int out_size, void* d_ws, size_t ws_size,
                              hipStream_t stream) {
    const float* X    = (const float*)d_in[0];
    const float* W    = (const float*)d_in[1];
    const float* bias = (const float*)d_in[2];
    float* Out = (float*)d_out;

    // Workspace layout (bytes), total ~142.6 MiB used:
    //   [0, 67.1M):  S  (scores)  -- aliases Xb [0,25.2M) + Wt [25.2M,28.7M),
    //                                which are dead before score_gemm runs.
    //   [67.1M ...): Q | K | Vt   (25.2M each)
    char* ws = (char*)d_ws;
    ushort* S  = (ushort*)ws;
    ushort* Xb = (ushort*)ws;
    ushort* Wt = (ushort*)(ws + (size_t)BATCH * SEQ * DMODEL * 2);
    ushort* Qs = (ushort*)(ws + (size_t)BATCH * SEQ * SEQ * 2);
    ushort* Kb = Qs + (size_t)BATCH * SEQ * DMODEL;
    ushort* Vt = Kb + (size_t)BATCH * SEQ * DMODEL;

    const int LDSB = 131072;
    (void)hipFuncSetAttribute((const void*)gemm8<0, 12>,
                              hipFuncAttributeMaxDynamicSharedMemorySize, LDSB);
    (void)hipFuncSetAttribute((const void*)gemm8<1, 12>,
                              hipFuncAttributeMaxDynamicSharedMemorySize, LDSB);
    (void)hipFuncSetAttribute((const void*)gemm8<2, 32>,
                              hipFuncAttributeMaxDynamicSharedMemorySize, LDSB);

    convert_x<<<2048, 256, 0, stream>>>(X, Xb);
    convert_wt<<<dim3(NQKV / 32, DMODEL / 32), 256, 0, stream>>>(W, Wt);
    gemm8<0, 12><<<dim3(64, 9), 512, LDSB, stream>>>(
        Xb, Wt, bias, Qs, Kb, Vt, DMODEL, DMODEL);
    gemm8<1, 12><<<dim3(8, 8, 8), 512, LDSB, stream>>>(
        Qs, Kb, nullptr, S, nullptr, nullptr, DMODEL, DMODEL);
    softmax_rows<<<BATCH * SEQ, 256, 0, stream>>>(S);
    gemm8<2, 32><<<dim3(8, 3, 8), 512, LDSB, stream>>>(
        S, Vt, nullptr, Out, nullptr, nullptr, SEQ, SEQ);
}